// Round 3
// baseline (21266.942 us; speedup 1.0000x reference)
//
#include <hip/hip_runtime.h>
#include <hip/hip_bf16.h>
#include <math.h>

typedef unsigned int u32;
typedef __hip_bfloat16 bf16;

#define CDIM   768
#define BATCH  32
#define SEQ    513
#define NT     (BATCH*SEQ)     // 16416 rows incl cls
#define NR     16384           // BG
#define NHEAD  12
#define HD     64
#define FFDIM  3072
#define NCLUST 2048
#define D1SEG  6272
#define NVIEW  6
#define MIDD   12
#define H1N    6
#define N1V    128
#define NB1    128
#define CHROWS 4104            // FFN row chunk (4 chunks)

// ---------------- workspace layout (float-slot offsets; total 57,446,528 fs ≈ 229.8 MB) ----
#define A_FS      ((size_t)0)          // 6,303,744 fs : y / obuf / y2 / yview  (NT*768 bf16)
#define B_FS      ((size_t)6303744)    // 18,911,232 fs: qkv bf16 | h+xffn bf16 | qkv1+o1+svs
#define X1_FS     ((size_t)25214976)   // 6,303,744 fs : x1 bf16
#define AH_FS     ((size_t)31518720)   // 262,656 fs   : ah fp32
#define D_FS      ((size_t)31781376)   // 9,640,064 fs : seg sum / max / cnt (sum+max=9,633,792; cnt=6,272)
#define DMAX_FS   (D_FS + 4816896)
#define DCNT_FS   (D_FS + 9633792)
#define DTOT_FS   9640064
#define X3D_FS    ((size_t)(D_FS + DTOT_FS))          // 41,421,440 : 1,572,864 fs x3d fp32
#define BNV_FS    (X3D_FS + 1572864)                  // 42,994,304 : 14,450,688 fs bnv bf16
#define STATM_FS  (BNV_FS + 14450688)                 // 57,444,992
#define STATR_FS  (STATM_FS + 768)                    // 57,445,760 (+768 -> 57,446,528 total)

__device__ inline float b2f(bf16 v){ return __bfloat162float(v); }
__device__ inline float bfu(unsigned short u){ return __uint_as_float(((u32)u)<<16); }
__device__ inline float ldv(const float* p, size_t i){ return p[i]; }
__device__ inline float ldv(const bf16*  p, size_t i){ return __bfloat162float(p[i]); }
__device__ inline void  stv(float* p, size_t i, float v){ p[i] = v; }
__device__ inline void  stv(bf16*  p, size_t i, float v){ p[i] = __float2bfloat16(v); }

// ---------------- kernels ----------------

__global__ __launch_bounds__(256) void k_zero(float* p, int n){
    for (int i = blockIdx.x*256 + threadIdx.x; i < n; i += gridDim.x*256) p[i] = 0.0f;
}

// LayerNorm over C=768, one block per row; input fp32/bf16, optional token-row map; out bf16
template<typename TI, bool MAP>
__global__ __launch_bounds__(256) void k_ln(const TI* __restrict__ in, bf16* __restrict__ out,
                                            const float* __restrict__ g, const float* __restrict__ b){
    int i = blockIdx.x;
    size_t ri = MAP ? (size_t)(i + (i>>9) + 1) : (size_t)i;
    int tid = threadIdx.x;
    const TI* r = in + ri*CDIM;
    float v0 = ldv(r,(size_t)tid), v1 = ldv(r,(size_t)tid+256), v2 = ldv(r,(size_t)tid+512);
    float s  = v0+v1+v2;
    float s2 = v0*v0+v1*v1+v2*v2;
    __shared__ float t1[4], t2[4];
    #pragma unroll
    for (int o=32;o;o>>=1){ s += __shfl_down(s,o,64); s2 += __shfl_down(s2,o,64); }
    int lane = tid & 63, wid = tid >> 6;
    if (!lane){ t1[wid]=s; t2[wid]=s2; }
    __syncthreads();
    float S  = t1[0]+t1[1]+t1[2]+t1[3];
    float S2 = t2[0]+t2[1]+t2[2]+t2[3];
    float m  = S * (1.0f/CDIM);
    float var = S2 * (1.0f/CDIM) - m*m;
    float rstd = rsqrtf(var + 1e-5f);
    bf16* o_ = out + (size_t)i*CDIM;
    stv(o_,(size_t)tid,     (v0-m)*rstd*g[tid]     + b[tid]);
    stv(o_,(size_t)tid+256, (v1-m)*rstd*g[tid+256] + b[tid+256]);
    stv(o_,(size_t)tid+512, (v2-m)*rstd*g[tid+512] + b[tid+512]);
}

// out[M,N] = A[M,K](bf16) @ W[N,K]^T(f32) + bias ; ACT==1 -> quick_gelu ; res(f32)!=null -> += res
#define TM 64
#define TN 64
#define TKK 16
template<typename TO, int ACT>
__global__ __launch_bounds__(256) void k_gemm(const bf16* __restrict__ A, const float* __restrict__ W,
                                              const float* __restrict__ bias, const float* __restrict__ res,
                                              TO* __restrict__ out, int M, int N, int K){
    __shared__ __align__(16) float As[TKK][TM+4];
    __shared__ __align__(16) float Ws[TKK][TN+4];
    int bm = blockIdx.y*TM, bn = blockIdx.x*TN;
    int tid = threadIdx.x;
    int tr = tid >> 4, tc = tid & 15;
    float acc[4][4];
    #pragma unroll
    for (int ii=0;ii<4;ii++)
        #pragma unroll
        for (int jj=0;jj<4;jj++) acc[ii][jj]=0.0f;
    for (int k0=0;k0<K;k0+=TKK){
        #pragma unroll
        for (int t=0;t<4;t++){
            int e = tid + t*256;
            int i = e >> 4, j = e & 15;
            int ar = bm + i;
            As[j][i] = (ar < M) ? b2f(A[(size_t)ar*K + k0 + j]) : 0.0f;
            int wr = bn + i;
            Ws[j][i] = (wr < N) ? W[(size_t)wr*K + k0 + j] : 0.0f;
        }
        __syncthreads();
        #pragma unroll
        for (int kk=0;kk<TKK;kk++){
            const float4 av = *(const float4*)&As[kk][tr<<2];
            const float4 bv = *(const float4*)&Ws[kk][tc<<2];
            const float a_[4] = {av.x,av.y,av.z,av.w};
            const float b_[4] = {bv.x,bv.y,bv.z,bv.w};
            #pragma unroll
            for (int ii=0;ii<4;ii++)
                #pragma unroll
                for (int jj=0;jj<4;jj++) acc[ii][jj] += a_[ii]*b_[jj];
        }
        __syncthreads();
    }
    int r0 = bm + (tr<<2), c0 = bn + (tc<<2);
    #pragma unroll
    for (int ii=0;ii<4;ii++){
        int r = r0+ii;
        if (r < M){
            #pragma unroll
            for (int jj=0;jj<4;jj++){
                int c = c0+jj;
                if (c < N){
                    float v = acc[ii][jj] + bias[c];
                    if (ACT == 1) v = v / (1.0f + expf(-1.702f*v));
                    if (res) v += res[(size_t)r*N + c];
                    stv(out, (size_t)r*N + c, v);
                }
            }
        }
    }
}

// main MHA: block per (q=blockIdx.x, h=blockIdx.y, b=blockIdx.z); qkv bf16 in, obuf bf16 out
__global__ __launch_bounds__(256) void k_attn(const bf16* __restrict__ qkv, bf16* __restrict__ obuf){
    int s = blockIdx.x, h = blockIdx.y, b = blockIdx.z;
    __shared__ float lq[HD];
    __shared__ float sc[SEQ];
    __shared__ float red[256];
    int tid = threadIdx.x;
    size_t base = (size_t)b*SEQ*2304;
    const bf16* Q  = qkv + base + (size_t)s*2304 + h*HD;
    const bf16* Kp = qkv + base + 768  + h*HD;
    const bf16* Vp = qkv + base + 1536 + h*HD;
    if (tid < HD) lq[tid] = b2f(Q[tid]);
    __syncthreads();
    float lmax = -1e30f;
    for (int k=tid; k<SEQ; k+=256){
        const ushort4* kr = (const ushort4*)(Kp + (size_t)k*2304);
        float d = 0.0f;
        #pragma unroll
        for (int dd=0; dd<16; dd++){
            ushort4 kv = kr[dd];
            d += lq[dd*4+0]*bfu(kv.x) + lq[dd*4+1]*bfu(kv.y)
               + lq[dd*4+2]*bfu(kv.z) + lq[dd*4+3]*bfu(kv.w);
        }
        d *= 0.125f;
        sc[k] = d;
        lmax = fmaxf(lmax, d);
    }
    red[tid]=lmax; __syncthreads();
    for (int st=128; st; st>>=1){ if (tid<st) red[tid]=fmaxf(red[tid],red[tid+st]); __syncthreads(); }
    float m = red[0]; __syncthreads();
    float ls = 0.0f;
    for (int k=tid; k<SEQ; k+=256){ float p = expf(sc[k]-m); sc[k]=p; ls+=p; }
    red[tid]=ls; __syncthreads();
    for (int st=128; st; st>>=1){ if (tid<st) red[tid]+=red[tid+st]; __syncthreads(); }
    float inv = 1.0f/red[0]; __syncthreads();
    int d = tid & 63, ch = tid >> 6;
    float acc = 0.0f;
    for (int k=ch; k<SEQ; k+=4) acc += sc[k]*b2f(Vp[(size_t)k*2304 + d]);
    red[tid]=acc; __syncthreads();
    if (tid < 64){
        float o = (red[tid]+red[tid+64]+red[tid+128]+red[tid+192])*inv;
        obuf[((size_t)(b*SEQ+s))*CDIM + h*HD + tid] = __float2bfloat16(o);
    }
}

// x2 = x1 + xffn + 0.5*(ah @ Wa2^T + ba2) -> d_out (fp32); block per row
__global__ __launch_bounds__(256) void k_comb(const bf16* __restrict__ x1, const bf16* __restrict__ xffn,
                                              const float* __restrict__ ah, const float* __restrict__ Wa2,
                                              const float* __restrict__ ba2, float* __restrict__ x2){
    int i = blockIdx.x; int tid = threadIdx.x;
    __shared__ float ar[16];
    if (tid < 16) ar[tid] = ah[(size_t)i*16 + tid];
    __syncthreads();
    for (int c=tid; c<CDIM; c+=256){
        const float* w = Wa2 + (size_t)c*16;
        float a = ba2[c];
        #pragma unroll
        for (int mm=0; mm<16; mm++) a += ar[mm]*w[mm];
        size_t o = (size_t)i*CDIM + c;
        x2[o] = b2f(x1[o]) + b2f(xffn[o]) + 0.5f*a;
    }
}

// cluster segment accumulate: block per token row, reads d_out with row map
__global__ __launch_bounds__(256) void k_segacc(const float* __restrict__ outx, const int* __restrict__ idx,
                                                float* __restrict__ ssum, u32* __restrict__ smax,
                                                int* __restrict__ scnt){
    int i = blockIdx.x; int tid = threadIdx.x;
    int sg = idx[i];
    if (tid == 0) atomicAdd(&scnt[sg], 1);
    size_t rb = (size_t)(i + (i>>9) + 1)*CDIM, sb = (size_t)sg*CDIM;
    for (int c=tid; c<CDIM; c+=256){
        float v = outx[rb+c];
        atomicAdd(&ssum[sb+c], v);
        u32 u = __float_as_uint(v);
        u = (u & 0x80000000u) ? ~u : (u | 0x80000000u);
        atomicMax(&smax[sb+c], u);
    }
}

__global__ __launch_bounds__(256) void k_segcomb(const float* __restrict__ ssum, const u32* __restrict__ smax,
                                                 const int* __restrict__ scnt, float* __restrict__ outp, int n){
    int i = blockIdx.x*256 + threadIdx.x;
    if (i >= n) return;
    int sg = i / CDIM;
    int c_ = scnt[sg];
    float mx = 0.0f;
    u32 u = smax[i];
    if (c_ > 0 && u != 0u){
        u32 bits = (u & 0x80000000u) ? (u & 0x7FFFFFFFu) : ~u;
        mx = __uint_as_float(bits);
    }
    float mean = ssum[i] / (float)(c_ > 1 ? c_ : 1);
    outp[i] = mx + mean;
}

__global__ __launch_bounds__(256) void k_colstats(const float* __restrict__ in, int rows,
                                                  float* __restrict__ m_out, float* __restrict__ r_out){
    int c = blockIdx.x*256 + threadIdx.x;
    if (c >= CDIM) return;
    float s = 0.0f, s2 = 0.0f;
    for (int r=0; r<rows; r++){
        float v = in[(size_t)r*CDIM + c];
        s += v; s2 += v*v;
    }
    float mean = s / (float)rows;
    float var  = s2 / (float)rows - mean*mean;
    m_out[c] = mean;
    r_out[c] = rsqrtf(fmaxf(var, 0.0f) + 1e-5f);
}

template<typename TO>
__global__ __launch_bounds__(256) void k_bngelu(const float* __restrict__ in, TO* __restrict__ outp,
                                                const float* __restrict__ m, const float* __restrict__ r,
                                                const float* __restrict__ g, const float* __restrict__ b, int n){
    int i = blockIdx.x*256 + threadIdx.x;
    if (i >= n) return;
    int c = i - (i/CDIM)*CDIM;
    float y = (in[i]-m[c])*r[c]*g[c] + b[c];
    stv(outp, (size_t)i, 0.5f*y*(1.0f + erff(y*0.70710678118654752f)));
}

// per-view micro attention: block per (segblock, head), 128 threads (one q row each)
__global__ __launch_bounds__(128) void k_attnv(const float* __restrict__ qkv1,
                                               const unsigned char* __restrict__ maskv,
                                               float* __restrict__ o1){
    int blk = blockIdx.x, h = blockIdx.y;
    int n = threadIdx.x;
    __shared__ float Ks[N1V][2], Vs[N1V][2];
    const float* rowp = qkv1 + (size_t)(blk*N1V + n)*36;
    float q0 = rowp[h*2+0], q1 = rowp[h*2+1];
    Ks[n][0] = rowp[12 + h*2 + 0]; Ks[n][1] = rowp[12 + h*2 + 1];
    Vs[n][0] = rowp[24 + h*2 + 0]; Vs[n][1] = rowp[24 + h*2 + 1];
    __syncthreads();
    const unsigned char* mrow = maskv + ((size_t)blk*N1V + n)*N1V;
    const float scale = 0.28867513459481287f; // 12^-0.5
    float m = -1e30f;
    for (int k=0; k<N1V; k++){
        float s = (q0*Ks[k][0] + q1*Ks[k][1])*scale + (mrow[k] ? -100000.0f : 0.0f);
        m = fmaxf(m, s);
    }
    float l = 0.0f, o0 = 0.0f, o1v = 0.0f;
    for (int k=0; k<N1V; k++){
        float s = (q0*Ks[k][0] + q1*Ks[k][1])*scale + (mrow[k] ? -100000.0f : 0.0f);
        float p = expf(s - m);
        l += p; o0 += p*Vs[k][0]; o1v += p*Vs[k][1];
    }
    float inv = 1.0f/l;
    float* orow = o1 + (size_t)(blk*N1V + n)*MIDD + h*2;
    orow[0] = o0*inv; orow[1] = o1v*inv;
}

// fused: flat = o1 @ projw^T + projb + feat(d_out mapped); then segment-accumulate
__global__ __launch_bounds__(256) void k_flatseg(const float* __restrict__ o1, const float* __restrict__ Wp,
                                                 const float* __restrict__ bp, const float* __restrict__ outx,
                                                 const int* __restrict__ idx,
                                                 float* __restrict__ ssum, u32* __restrict__ smax,
                                                 int* __restrict__ scnt){
    int i = blockIdx.x; int tid = threadIdx.x;
    __shared__ float orow[MIDD];
    if (tid < MIDD) orow[tid] = o1[(size_t)i*MIDD + tid];
    __syncthreads();
    int sg = idx[i];
    if (tid == 0) atomicAdd(&scnt[sg], 1);
    size_t rb = (size_t)(i + (i>>9) + 1)*CDIM, sb = (size_t)sg*CDIM;
    for (int c=tid; c<CDIM; c+=256){
        const float* w = Wp + (size_t)c*MIDD;
        float a = bp[c];
        #pragma unroll
        for (int mm=0; mm<MIDD; mm++) a += orow[mm]*w[mm];
        a += outx[rb+c];
        atomicAdd(&ssum[sb+c], a);
        u32 u = __float_as_uint(a);
        u = (u & 0x80000000u) ? ~u : (u | 0x80000000u);
        atomicMax(&smax[sb+c], u);
    }
}

// cossim + sims-normalize + weighted sum + residual; block per token row; in-place on d_out
__global__ __launch_bounds__(256) void k_final(float* __restrict__ outx, const float* __restrict__ x3d,
                                               const bf16* __restrict__ bnv, const int* __restrict__ cluster,
                                               const int* __restrict__ fgi){
    int i = blockIdx.x; int tid = threadIdx.x;
    int cl = cluster[i];
    const float* xr = x3d + (size_t)cl*CDIM;
    const bf16* pr[NVIEW];
    #pragma unroll
    for (int v=0; v<NVIEW; v++)
        pr[v] = bnv + ((size_t)v*D1SEG + fgi[(size_t)v*NR + i])*CDIM;
    size_t rb = (size_t)(i + (i>>9) + 1)*CDIM;
    float pv[NVIEW][3], ft[3];
    float dotv[NVIEW] = {0,0,0,0,0,0};
    float np2[NVIEW]  = {0,0,0,0,0,0};
    float nx2 = 0.0f;
    #pragma unroll
    for (int j=0; j<3; j++){
        int c = tid + j*256;
        float xv = xr[c]; nx2 += xv*xv;
        ft[j] = outx[rb + c];
        #pragma unroll
        for (int v=0; v<NVIEW; v++){
            float p = b2f(pr[v][c]); pv[v][j] = p;
            dotv[v] += p*xv; np2[v] += p*p;
        }
    }
    __shared__ float part[4*13];
    __shared__ float ssim[NVIEW];
    float vals[13];
    vals[0] = nx2;
    #pragma unroll
    for (int v=0; v<NVIEW; v++){ vals[1+v] = dotv[v]; vals[7+v] = np2[v]; }
    int lane = tid & 63, wid = tid >> 6;
    #pragma unroll
    for (int k=0; k<13; k++){
        float w = vals[k];
        #pragma unroll
        for (int o=32;o;o>>=1) w += __shfl_down(w,o,64);
        if (!lane) part[wid*13 + k] = w;
    }
    __syncthreads();
    if (tid == 0){
        float tot[13];
        #pragma unroll
        for (int k=0; k<13; k++) tot[k] = part[k] + part[13+k] + part[26+k] + part[39+k];
        float nb = fmaxf(sqrtf(tot[0]), 1e-8f);
        float sv[NVIEW]; float ssumv = 0.0f;
        #pragma unroll
        for (int v=0; v<NVIEW; v++){
            float na = fmaxf(sqrtf(tot[7+v]), 1e-8f);
            float cs = tot[1+v] / (na*nb);
            sv[v] = (cs + 1.0f)*0.5f;
            ssumv += sv[v];
        }
        #pragma unroll
        for (int v=0; v<NVIEW; v++) ssim[v] = sv[v]/ssumv;
    }
    __syncthreads();
    #pragma unroll
    for (int j=0; j<3; j++){
        int c = tid + j*256;
        float xs = 0.0f;
        #pragma unroll
        for (int v=0; v<NVIEW; v++) xs += ssim[v]*pv[v][j];
        outx[rb + c] = ft[j] + 0.3f*xs;
    }
}

// ---------------- host launcher ----------------
extern "C" void kernel_launch(void* const* d_in, const int* in_sizes, int n_in,
                              void* d_out, int out_size, void* d_ws, size_t ws_size,
                              hipStream_t stream){
    const float* x     = (const float*)d_in[0];
    const float* ln1g  = (const float*)d_in[1];
    const float* ln1b  = (const float*)d_in[2];
    const float* ln2g  = (const float*)d_in[3];
    const float* ln2b  = (const float*)d_in[4];
    const float* Wqkv  = (const float*)d_in[5];
    const float* bqkv  = (const float*)d_in[6];
    const float* Wo    = (const float*)d_in[7];
    const float* bo    = (const float*)d_in[8];
    const float* Wfc   = (const float*)d_in[9];
    const float* bfc   = (const float*)d_in[10];
    const float* Wproj = (const float*)d_in[11];
    const float* bproj = (const float*)d_in[12];
    const float* Wa1   = (const float*)d_in[13];
    const float* ba1   = (const float*)d_in[14];
    const float* Wa2   = (const float*)d_in[15];
    const float* ba2   = (const float*)d_in[16];
    const float* bn3dg = (const float*)d_in[17];
    const float* bn3db = (const float*)d_in[18];
    const float* bn1dg = (const float*)d_in[19];
    const float* bn1db = (const float*)d_in[20];
    const float* n3g   = (const float*)d_in[21];
    const float* n3b   = (const float*)d_in[22];
    const float* aqw   = (const float*)d_in[23];
    const float* aqb   = (const float*)d_in[24];
    const float* apw   = (const float*)d_in[25];
    const float* apb   = (const float*)d_in[26];
    const int*   cluster = (const int*)d_in[27];
    const int*   fgi     = (const int*)d_in[28];
    const unsigned char* mask = (const unsigned char*)d_in[29];
    float* out = (float*)d_out;
    float* ws  = (float*)d_ws;

    bf16*  yb    = (bf16*)(ws + A_FS);       // y / obuf / y2 / yview
    bf16*  qkvb  = (bf16*)(ws + B_FS);
    bf16*  hb    = (bf16*)(ws + B_FS);       // FFN hidden chunk (qkv dead)
    bf16*  xffb  = (bf16*)(ws + B_FS + 6303744);
    float* qkv1  = ws + B_FS;                // phase 2 (all of B dead)
    float* o1    = ws + B_FS + 589824;
    float* svs   = ws + B_FS + 786432;
    bf16*  x1b   = (bf16*)(ws + X1_FS);
    float* ah    = ws + AH_FS;
    float* Dsum  = ws + D_FS;
    u32*   Dmax  = (u32*)(ws + DMAX_FS);
    int*   Dcnt  = (int*)(ws + DCNT_FS);
    float* x3d   = ws + X3D_FS;
    bf16*  bnv   = (bf16*)(ws + BNV_FS);
    float* statm = ws + STATM_FS;
    float* statr = ws + STATR_FS;

    // 1. LN1 (x fp32 -> y bf16)
    k_ln<float,false><<<NT, 256, 0, stream>>>(x, yb, ln1g, ln1b);
    // 2. qkv GEMM (bf16 out)
    k_gemm<bf16,0><<<dim3(2304/TN, (NT+TM-1)/TM), 256, 0, stream>>>(yb, Wqkv, bqkv, nullptr, qkvb, NT, 2304, 768);
    // 3. attention -> obuf (A region; y dead)
    k_attn<<<dim3(SEQ, NHEAD, BATCH), 256, 0, stream>>>(qkvb, yb);
    // 4. o-proj + residual(x) -> x1 bf16
    k_gemm<bf16,0><<<dim3(768/TN, (NT+TM-1)/TM), 256, 0, stream>>>(yb, Wo, bo, x, x1b, NT, 768, 768);
    // 5. LN2 (x1 bf16 -> y2 bf16 in A)
    k_ln<bf16,false><<<NT, 256, 0, stream>>>(x1b, yb, ln2g, ln2b);
    // 6/7. FFN in 4 row-chunks (h chunk in B; qkv dead)
    for (int cch=0; cch<4; cch++){
        const bf16* a2 = yb + (size_t)cch*CHROWS*CDIM;
        bf16* xo = xffb + (size_t)cch*CHROWS*CDIM;
        k_gemm<bf16,1><<<dim3(FFDIM/TN, (CHROWS+TM-1)/TM), 256, 0, stream>>>(a2, Wfc, bfc, nullptr, hb, CHROWS, FFDIM, 768);
        k_gemm<bf16,0><<<dim3(768/TN, (CHROWS+TM-1)/TM), 256, 0, stream>>>(hb, Wproj, bproj, nullptr, xo, CHROWS, 768, FFDIM);
    }
    // 8. adapt hidden (fp32 out, quick_gelu)
    k_gemm<float,1><<<dim3(1, (NT+TM-1)/TM), 256, 0, stream>>>(xffb, Wa1, ba1, nullptr, ah, NT, 16, 768);
    // 9. combine -> d_out (x2; cls rows final)
    k_comb<<<NT, 256, 0, stream>>>(x1b, xffb, ah, Wa2, ba2, out);
    // 10. cluster segment max/mean + bn_gelu -> x3d
    k_zero<<<4096, 256, 0, stream>>>(Dsum, DTOT_FS);
    k_segacc<<<NR, 256, 0, stream>>>(out, cluster, Dsum, Dmax, Dcnt);
    k_segcomb<<<(NCLUST*CDIM+255)/256, 256, 0, stream>>>(Dsum, Dmax, Dcnt, x3d, NCLUST*CDIM);
    k_colstats<<<3, 256, 0, stream>>>(x3d, NCLUST, statm, statr);
    k_bngelu<float><<<(NCLUST*CDIM+255)/256, 256, 0, stream>>>(x3d, x3d, statm, statr, bn3dg, bn3db, NCLUST*CDIM);
    // 11. views
    for (int v=0; v<NVIEW; v++){
        k_ln<float,true><<<NR, 256, 0, stream>>>(out, yb, n3g + v*CDIM, n3b + v*CDIM);
        k_gemm<float,0><<<dim3(1, NR/TM), 256, 0, stream>>>(yb, aqw + (size_t)v*36*768, aqb + v*36, nullptr, qkv1, NR, 36, 768);
        k_attnv<<<dim3(NB1, H1N), 128, 0, stream>>>(qkv1, mask + (size_t)v*NB1*N1V*N1V, o1);
        k_zero<<<4096, 256, 0, stream>>>(Dsum, DTOT_FS);
        k_flatseg<<<NR, 256, 0, stream>>>(o1, apw + (size_t)v*CDIM*MIDD, apb + v*CDIM, out,
                                          fgi + (size_t)v*NR, Dsum, Dmax, Dcnt);
        k_segcomb<<<(D1SEG*CDIM+255)/256, 256, 0, stream>>>(Dsum, Dmax, Dcnt, svs, D1SEG*CDIM);
        k_colstats<<<3, 256, 0, stream>>>(svs, D1SEG, statm, statr);
        k_bngelu<bf16><<<(D1SEG*CDIM+255)/256, 256, 0, stream>>>(svs, bnv + (size_t)v*D1SEG*CDIM, statm, statr,
                                                                 bn1dg + v*CDIM, bn1db + v*CDIM, D1SEG*CDIM);
    }
    // 12. final combine (in-place on d_out)
    k_final<<<NR, 256, 0, stream>>>(out, x3d, bnv, cluster, fgi);
}

// Round 4
// 3082.097 us; speedup vs baseline: 6.9002x; 6.9002x over previous
//
#include <hip/hip_runtime.h>
#include <hip/hip_bf16.h>
#include <math.h>

typedef unsigned int u32;
typedef __hip_bfloat16 bf16;
typedef __attribute__((ext_vector_type(8))) short bh8;
typedef __attribute__((ext_vector_type(4))) float fx4;

#define CDIM   768
#define BATCH  32
#define SEQ    513
#define NT     (BATCH*SEQ)     // 16416 rows incl cls
#define NR     16384           // BG
#define NHEAD  12
#define HD     64
#define FFDIM  3072
#define NCLUST 2048
#define D1SEG  6272
#define NVIEW  6
#define MIDD   12
#define H1N    6
#define N1V    128
#define NB1    128
#define CHROWS 4104            // FFN row chunk (4 chunks)

// ---------------- workspace layout (float-slot offsets; total 57,446,528 fs ≈ 229.8 MB) ----
#define A_FS      ((size_t)0)          // 6,303,744 fs : y / obuf / y2 / yview  (NT*768 bf16)
#define B_FS      ((size_t)6303744)    // 18,911,232 fs: qkv bf16 | h+xffn bf16 | qkv1+o1+svs
#define X1_FS     ((size_t)25214976)   // 6,303,744 fs : x1 bf16
#define AH_FS     ((size_t)31518720)   // 262,656 fs   : ah fp32
#define D_FS      ((size_t)31781376)   // 9,640,064 fs : seg sum/max/cnt  | bf16 weights (phase 1)
#define DMAX_FS   (D_FS + 4816896)
#define DCNT_FS   (D_FS + 9633792)
#define DTOT_FS   9640064
#define X3D_FS    ((size_t)(D_FS + DTOT_FS))          // 1,572,864 fs x3d fp32
#define BNV_FS    (X3D_FS + 1572864)                  // 14,450,688 fs bnv bf16
#define STATM_FS  (BNV_FS + 14450688)                 // 768 (sum -> mean)
#define STATR_FS  (STATM_FS + 768)                    // 768 (sumsq -> rstd)

__device__ inline float b2f(bf16 v){ return __bfloat162float(v); }
__device__ inline float ldv(const float* p, size_t i){ return p[i]; }
__device__ inline float ldv(const bf16*  p, size_t i){ return __bfloat162float(p[i]); }
__device__ inline void  stv(float* p, size_t i, float v){ p[i] = v; }
__device__ inline void  stv(bf16*  p, size_t i, float v){ p[i] = __float2bfloat16(v); }
__device__ inline short f2bs(float f){ bf16 h = __float2bfloat16(f); return *(short*)&h; }

// ---------------- utility ----------------

__global__ __launch_bounds__(256) void k_zero(float* p, int n){
    for (int i = blockIdx.x*256 + threadIdx.x; i < n; i += gridDim.x*256) p[i] = 0.0f;
}

__global__ __launch_bounds__(256) void k_f2b(const float* __restrict__ in, bf16* __restrict__ out, int n){
    for (int i = blockIdx.x*256 + threadIdx.x; i < n; i += gridDim.x*256)
        out[i] = __float2bfloat16(in[i]);
}

// LayerNorm over C=768, one block per row; out bf16
template<typename TI, bool MAP>
__global__ __launch_bounds__(256) void k_ln(const TI* __restrict__ in, bf16* __restrict__ out,
                                            const float* __restrict__ g, const float* __restrict__ b){
    int i = blockIdx.x;
    size_t ri = MAP ? (size_t)(i + (i>>9) + 1) : (size_t)i;
    int tid = threadIdx.x;
    const TI* r = in + ri*CDIM;
    float v0 = ldv(r,(size_t)tid), v1 = ldv(r,(size_t)tid+256), v2 = ldv(r,(size_t)tid+512);
    float s  = v0+v1+v2;
    float s2 = v0*v0+v1*v1+v2*v2;
    __shared__ float t1[4], t2[4];
    #pragma unroll
    for (int o=32;o;o>>=1){ s += __shfl_down(s,o,64); s2 += __shfl_down(s2,o,64); }
    int lane = tid & 63, wid = tid >> 6;
    if (!lane){ t1[wid]=s; t2[wid]=s2; }
    __syncthreads();
    float S  = t1[0]+t1[1]+t1[2]+t1[3];
    float S2 = t2[0]+t2[1]+t2[2]+t2[3];
    float m  = S * (1.0f/CDIM);
    float var = S2 * (1.0f/CDIM) - m*m;
    float rstd = rsqrtf(var + 1e-5f);
    bf16* o_ = out + (size_t)i*CDIM;
    stv(o_,(size_t)tid,     (v0-m)*rstd*g[tid]     + b[tid]);
    stv(o_,(size_t)tid+256, (v1-m)*rstd*g[tid+256] + b[tid+256]);
    stv(o_,(size_t)tid+512, (v2-m)*rstd*g[tid+512] + b[tid+512]);
}

// ---------------- MFMA GEMM: out[M,N] = A[M,K](bf16) @ W[N,K]^T(bf16) + bias ----------------
// 128x128 block tile, 4 waves each 64x64 (4x4 of 16x16x32 mfma). LDS row stride 40 (aligned b128 reads).
#define GSTR 40
template<typename TO, int ACT, int RES>
__global__ __launch_bounds__(256) void k_gemm_mfma(const bf16* __restrict__ A, const bf16* __restrict__ W,
                                                   const float* __restrict__ bias, const float* __restrict__ res,
                                                   TO* __restrict__ out, int M, int N, int K){
    __shared__ short As[128*GSTR];
    __shared__ short Ws[128*GSTR];
    int bm = blockIdx.y*128, bn = blockIdx.x*128;
    int tid = threadIdx.x, wid = tid>>6, lane = tid&63, quad = lane>>4, l16 = lane&15;
    int wr = (wid>>1)*64, wc = (wid&1)*64;
    fx4 acc[4][4];
    #pragma unroll
    for (int i=0;i<4;i++)
        #pragma unroll
        for (int j=0;j<4;j++) acc[i][j] = (fx4){0.f,0.f,0.f,0.f};
    int sr = tid>>1, sc0 = (tid&1)*16;
    bool aval = (bm+sr) < M;
    bool wval = (bn+sr) < N;
    const bf16* arow = A + (size_t)(aval ? bm+sr : 0)*K;
    const bf16* wrow = W + (size_t)(wval ? bn+sr : 0)*K;
    const bh8 zv = {0,0,0,0,0,0,0,0};
    for (int k0=0; k0<K; k0+=32){
        bh8 a0 = aval ? *(const bh8*)(arow + k0 + sc0)     : zv;
        bh8 a1 = aval ? *(const bh8*)(arow + k0 + sc0 + 8) : zv;
        bh8 w0 = wval ? *(const bh8*)(wrow + k0 + sc0)     : zv;
        bh8 w1 = wval ? *(const bh8*)(wrow + k0 + sc0 + 8) : zv;
        *(bh8*)&As[sr*GSTR + sc0]     = a0;
        *(bh8*)&As[sr*GSTR + sc0 + 8] = a1;
        *(bh8*)&Ws[sr*GSTR + sc0]     = w0;
        *(bh8*)&Ws[sr*GSTR + sc0 + 8] = w1;
        __syncthreads();
        bh8 af[4], bf_[4];
        #pragma unroll
        for (int i=0;i<4;i++) af[i]  = *(const bh8*)&As[(wr + i*16 + l16)*GSTR + quad*8];
        #pragma unroll
        for (int j=0;j<4;j++) bf_[j] = *(const bh8*)&Ws[(wc + j*16 + l16)*GSTR + quad*8];
        #pragma unroll
        for (int i=0;i<4;i++)
            #pragma unroll
            for (int j=0;j<4;j++)
                acc[i][j] = __builtin_amdgcn_mfma_f32_16x16x32_bf16(af[i], bf_[j], acc[i][j], 0,0,0);
        __syncthreads();
    }
    #pragma unroll
    for (int i=0;i<4;i++){
        #pragma unroll
        for (int r=0;r<4;r++){
            int row = bm + wr + i*16 + quad*4 + r;
            if (row >= M) continue;
            #pragma unroll
            for (int j=0;j<4;j++){
                int col = bn + wc + j*16 + l16;
                if (col >= N) continue;
                float v = acc[i][j][r] + bias[col];
                if (ACT == 1) v = v / (1.0f + __expf(-1.702f*v));
                if (RES) v += res[(size_t)row*N + col];
                stv(out, (size_t)row*N + col, v);
            }
        }
    }
}

// ---------------- flash MFMA attention: block per (qtile, h, b) ----------------
#define KSTR 72
__global__ __launch_bounds__(256) void k_attn_mfma(const bf16* __restrict__ qkv, bf16* __restrict__ obuf){
    __shared__ short Ks[64*KSTR];      // [k][d]
    __shared__ short Vt[64*KSTR];      // [d][k]  (transposed)
    __shared__ short Ps[4*16*KSTR];    // per-wave P strip [16 q][64 k]
    int qt = blockIdx.x, h = blockIdx.y, b = blockIdx.z;
    int tid = threadIdx.x, wid = tid>>6, lane = tid&63, quad = lane>>4, l16 = lane&15;
    size_t base = (size_t)b*SEQ*2304;
    // Q fragments in registers for the whole kernel
    int q_own = qt*64 + wid*16 + l16;
    int q_cl  = q_own > 512 ? 512 : q_own;
    const bf16* qrow = qkv + base + (size_t)q_cl*2304 + h*HD;
    bh8 qa0 = *(const bh8*)(qrow + quad*8);
    bh8 qa1 = *(const bh8*)(qrow + 32 + quad*8);
    fx4 o[4];
    #pragma unroll
    for (int d=0; d<4; d++) o[d] = (fx4){0.f,0.f,0.f,0.f};
    float mrow[4] = {-1e30f,-1e30f,-1e30f,-1e30f};
    float lrow[4] = {0.f,0.f,0.f,0.f};
    int srow = tid>>2, d0 = (tid&3)*16;
    for (int kt=0; kt<9; kt++){
        // stage K [k][d] and V transposed [d][k]
        int kg = kt*64 + srow;
        if (kg < SEQ){
            const bf16* krow = qkv + base + 768  + (size_t)kg*2304 + h*HD;
            const bf16* vrow = qkv + base + 1536 + (size_t)kg*2304 + h*HD;
            bh8 kv0 = *(const bh8*)(krow + d0);
            bh8 kv1 = *(const bh8*)(krow + d0 + 8);
            bh8 vv0 = *(const bh8*)(vrow + d0);
            bh8 vv1 = *(const bh8*)(vrow + d0 + 8);
            *(bh8*)&Ks[srow*KSTR + d0]     = kv0;
            *(bh8*)&Ks[srow*KSTR + d0 + 8] = kv1;
            #pragma unroll
            for (int j=0;j<8;j++){ Vt[(d0+j)*KSTR + srow] = vv0[j]; Vt[(d0+8+j)*KSTR + srow] = vv1[j]; }
        } else {
            const bh8 zv = {0,0,0,0,0,0,0,0};
            *(bh8*)&Ks[srow*KSTR + d0]     = zv;
            *(bh8*)&Ks[srow*KSTR + d0 + 8] = zv;
            #pragma unroll
            for (int j=0;j<16;j++) Vt[(d0+j)*KSTR + srow] = 0;
        }
        __syncthreads();
        // S strip = Q(16x64) @ K^T -> 4 n-tiles of 16x16
        fx4 s[4];
        #pragma unroll
        for (int nt=0; nt<4; nt++){
            bh8 kb0 = *(const bh8*)&Ks[(nt*16+l16)*KSTR + quad*8];
            bh8 kb1 = *(const bh8*)&Ks[(nt*16+l16)*KSTR + 32 + quad*8];
            fx4 a = (fx4){0.f,0.f,0.f,0.f};
            a = __builtin_amdgcn_mfma_f32_16x16x32_bf16(qa0, kb0, a, 0,0,0);
            a = __builtin_amdgcn_mfma_f32_16x16x32_bf16(qa1, kb1, a, 0,0,0);
            s[nt] = a;
        }
        // scale + pad-mask (column = key index = l16 within n-tile)
        float tmax[4] = {-1e30f,-1e30f,-1e30f,-1e30f};
        #pragma unroll
        for (int nt=0; nt<4; nt++){
            bool ok = (kt*64 + nt*16 + l16) <= 512;
            #pragma unroll
            for (int r=0;r<4;r++){
                float v = ok ? s[nt][r]*0.125f : -1e30f;
                s[nt][r] = v;
                tmax[r] = fmaxf(tmax[r], v);
            }
        }
        #pragma unroll
        for (int msk=1; msk<16; msk<<=1)
            #pragma unroll
            for (int r=0;r<4;r++) tmax[r] = fmaxf(tmax[r], __shfl_xor(tmax[r], msk, 64));
        float al[4];
        #pragma unroll
        for (int r=0;r<4;r++){
            float mn = fmaxf(mrow[r], tmax[r]);
            al[r] = __expf(mrow[r] - mn);
            mrow[r] = mn;
        }
        float ps[4] = {0.f,0.f,0.f,0.f};
        #pragma unroll
        for (int nt=0; nt<4; nt++)
            #pragma unroll
            for (int r=0;r<4;r++){
                float p = __expf(s[nt][r] - mrow[r]);
                s[nt][r] = p;
                ps[r] += p;
            }
        #pragma unroll
        for (int msk=1; msk<16; msk<<=1)
            #pragma unroll
            for (int r=0;r<4;r++) ps[r] += __shfl_xor(ps[r], msk, 64);
        #pragma unroll
        for (int r=0;r<4;r++){
            lrow[r] = lrow[r]*al[r] + ps[r];
            #pragma unroll
            for (int d=0; d<4; d++) o[d][r] *= al[r];
        }
        // P strip C-layout -> LDS (A-layout round trip)
        #pragma unroll
        for (int nt=0; nt<4; nt++)
            #pragma unroll
            for (int r=0;r<4;r++)
                Ps[(wid*16 + quad*4 + r)*KSTR + nt*16 + l16] = f2bs(s[nt][r]);
        // PV: O(16x64) += P(16x64) @ V(64x64)
        bh8 pa0 = *(const bh8*)&Ps[(wid*16 + l16)*KSTR + quad*8];
        bh8 pa1 = *(const bh8*)&Ps[(wid*16 + l16)*KSTR + 32 + quad*8];
        #pragma unroll
        for (int dt=0; dt<4; dt++){
            bh8 vb0 = *(const bh8*)&Vt[(dt*16+l16)*KSTR + quad*8];
            bh8 vb1 = *(const bh8*)&Vt[(dt*16+l16)*KSTR + 32 + quad*8];
            o[dt] = __builtin_amdgcn_mfma_f32_16x16x32_bf16(pa0, vb0, o[dt], 0,0,0);
            o[dt] = __builtin_amdgcn_mfma_f32_16x16x32_bf16(pa1, vb1, o[dt], 0,0,0);
        }
        __syncthreads();
    }
    float inv[4];
    #pragma unroll
    for (int r=0;r<4;r++) inv[r] = 1.0f/lrow[r];
    #pragma unroll
    for (int r=0;r<4;r++){
        int q = qt*64 + wid*16 + quad*4 + r;
        if (q < SEQ){
            size_t ob = ((size_t)(b*SEQ+q))*CDIM + h*HD;
            #pragma unroll
            for (int dt=0; dt<4; dt++)
                obuf[ob + dt*16 + l16] = __float2bfloat16(o[dt][r]*inv[r]);
        }
    }
}

// scalar GEMM (small N): out[M,N] = A[M,K](bf16) @ W[N,K]^T(f32) + bias
#define TM 64
#define TN 64
#define TKK 16
template<typename TO, int ACT>
__global__ __launch_bounds__(256) void k_gemm(const bf16* __restrict__ A, const float* __restrict__ W,
                                              const float* __restrict__ bias, TO* __restrict__ out,
                                              int M, int N, int K){
    __shared__ __align__(16) float As[TKK][TM+4];
    __shared__ __align__(16) float Ws[TKK][TN+4];
    int bm = blockIdx.y*TM, bn = blockIdx.x*TN;
    int tid = threadIdx.x;
    int tr = tid >> 4, tc = tid & 15;
    float acc[4][4];
    #pragma unroll
    for (int ii=0;ii<4;ii++)
        #pragma unroll
        for (int jj=0;jj<4;jj++) acc[ii][jj]=0.0f;
    for (int k0=0;k0<K;k0+=TKK){
        #pragma unroll
        for (int t=0;t<4;t++){
            int e = tid + t*256;
            int i = e >> 4, j = e & 15;
            int ar = bm + i;
            As[j][i] = (ar < M) ? b2f(A[(size_t)ar*K + k0 + j]) : 0.0f;
            int wr = bn + i;
            Ws[j][i] = (wr < N) ? W[(size_t)wr*K + k0 + j] : 0.0f;
        }
        __syncthreads();
        #pragma unroll
        for (int kk=0;kk<TKK;kk++){
            const float4 av = *(const float4*)&As[kk][tr<<2];
            const float4 bv = *(const float4*)&Ws[kk][tc<<2];
            const float a_[4] = {av.x,av.y,av.z,av.w};
            const float b_[4] = {bv.x,bv.y,bv.z,bv.w};
            #pragma unroll
            for (int ii=0;ii<4;ii++)
                #pragma unroll
                for (int jj=0;jj<4;jj++) acc[ii][jj] += a_[ii]*b_[jj];
        }
        __syncthreads();
    }
    int r0 = bm + (tr<<2), c0 = bn + (tc<<2);
    #pragma unroll
    for (int ii=0;ii<4;ii++){
        int r = r0+ii;
        if (r < M){
            #pragma unroll
            for (int jj=0;jj<4;jj++){
                int c = c0+jj;
                if (c < N){
                    float v = acc[ii][jj] + bias[c];
                    if (ACT == 1) v = v / (1.0f + __expf(-1.702f*v));
                    stv(out, (size_t)r*N + c, v);
                }
            }
        }
    }
}

// x2 = x1 + xffn + 0.5*(ah @ Wa2^T + ba2) -> d_out (fp32); block per row
__global__ __launch_bounds__(256) void k_comb(const bf16* __restrict__ x1, const bf16* __restrict__ xffn,
                                              const float* __restrict__ ah, const float* __restrict__ Wa2,
                                              const float* __restrict__ ba2, float* __restrict__ x2){
    int i = blockIdx.x; int tid = threadIdx.x;
    __shared__ float ar[16];
    if (tid < 16) ar[tid] = ah[(size_t)i*16 + tid];
    __syncthreads();
    for (int c=tid; c<CDIM; c+=256){
        const float* w = Wa2 + (size_t)c*16;
        float a = ba2[c];
        #pragma unroll
        for (int mm=0; mm<16; mm++) a += ar[mm]*w[mm];
        size_t o = (size_t)i*CDIM + c;
        x2[o] = b2f(x1[o]) + b2f(xffn[o]) + 0.5f*a;
    }
}

// cluster segment accumulate: block per token row, reads d_out with row map
__global__ __launch_bounds__(256) void k_segacc(const float* __restrict__ outx, const int* __restrict__ idx,
                                                float* __restrict__ ssum, u32* __restrict__ smax,
                                                int* __restrict__ scnt){
    int i = blockIdx.x; int tid = threadIdx.x;
    int sg = idx[i];
    if (tid == 0) atomicAdd(&scnt[sg], 1);
    size_t rb = (size_t)(i + (i>>9) + 1)*CDIM, sb = (size_t)sg*CDIM;
    for (int c=tid; c<CDIM; c+=256){
        float v = outx[rb+c];
        atomicAdd(&ssum[sb+c], v);
        u32 u = __float_as_uint(v);
        u = (u & 0x80000000u) ? ~u : (u | 0x80000000u);
        atomicMax(&smax[sb+c], u);
    }
}

__global__ __launch_bounds__(256) void k_segcomb(const float* __restrict__ ssum, const u32* __restrict__ smax,
                                                 const int* __restrict__ scnt, float* __restrict__ outp, int n){
    int i = blockIdx.x*256 + threadIdx.x;
    if (i >= n) return;
    int sg = i / CDIM;
    int c_ = scnt[sg];
    float mx = 0.0f;
    u32 u = smax[i];
    if (c_ > 0 && u != 0u){
        u32 bits = (u & 0x80000000u) ? (u & 0x7FFFFFFFu) : ~u;
        mx = __uint_as_float(bits);
    }
    float mean = ssum[i] / (float)(c_ > 1 ? c_ : 1);
    outp[i] = mx + mean;
}

// two-stage column stats (sum/sumsq via atomics, then finalize)
__global__ __launch_bounds__(256) void k_colstats_part(const float* __restrict__ in, int rows,
                                                       float* __restrict__ sumv, float* __restrict__ sumsq){
    int c = blockIdx.x*256 + threadIdx.x;
    if (c >= CDIM) return;
    int chunk = (rows + 31) >> 5;
    int r0 = blockIdx.y*chunk;
    int r1 = r0 + chunk; if (r1 > rows) r1 = rows;
    float s = 0.0f, s2 = 0.0f;
    for (int r=r0; r<r1; r++){
        float v = in[(size_t)r*CDIM + c];
        s += v; s2 += v*v;
    }
    atomicAdd(&sumv[c], s);
    atomicAdd(&sumsq[c], s2);
}

__global__ __launch_bounds__(256) void k_colfin(float* __restrict__ sumv, float* __restrict__ sumsq, int rows){
    int c = blockIdx.x*256 + threadIdx.x;
    if (c >= CDIM) return;
    float m = sumv[c] / (float)rows;
    float var = sumsq[c] / (float)rows - m*m;
    sumv[c]  = m;
    sumsq[c] = rsqrtf(fmaxf(var, 0.0f) + 1e-5f);
}

template<typename TO>
__global__ __launch_bounds__(256) void k_bngelu(const float* __restrict__ in, TO* __restrict__ outp,
                                                const float* __restrict__ m, const float* __restrict__ r,
                                                const float* __restrict__ g, const float* __restrict__ b, int n){
    int i = blockIdx.x*256 + threadIdx.x;
    if (i >= n) return;
    int c = i - (i/CDIM)*CDIM;
    float y = (in[i]-m[c])*r[c]*g[c] + b[c];
    stv(outp, (size_t)i, 0.5f*y*(1.0f + erff(y*0.70710678118654752f)));
}

// per-view micro attention: block per (segblock, head), 128 threads (one q row each)
__global__ __launch_bounds__(128) void k_attnv(const float* __restrict__ qkv1,
                                               const unsigned char* __restrict__ maskv,
                                               float* __restrict__ o1){
    int blk = blockIdx.x, h = blockIdx.y;
    int n = threadIdx.x;
    __shared__ float Ksv[N1V][2], Vsv[N1V][2];
    const float* rowp = qkv1 + (size_t)(blk*N1V + n)*36;
    float q0 = rowp[h*2+0], q1 = rowp[h*2+1];
    Ksv[n][0] = rowp[12 + h*2 + 0]; Ksv[n][1] = rowp[12 + h*2 + 1];
    Vsv[n][0] = rowp[24 + h*2 + 0]; Vsv[n][1] = rowp[24 + h*2 + 1];
    __syncthreads();
    const unsigned char* mrow = maskv + ((size_t)blk*N1V + n)*N1V;
    const float scale = 0.28867513459481287f; // 12^-0.5
    float m = -1e30f;
    for (int k=0; k<N1V; k++){
        float s = (q0*Ksv[k][0] + q1*Ksv[k][1])*scale + (mrow[k] ? -100000.0f : 0.0f);
        m = fmaxf(m, s);
    }
    float l = 0.0f, o0 = 0.0f, o1v = 0.0f;
    for (int k=0; k<N1V; k++){
        float s = (q0*Ksv[k][0] + q1*Ksv[k][1])*scale + (mrow[k] ? -100000.0f : 0.0f);
        float p = __expf(s - m);
        l += p; o0 += p*Vsv[k][0]; o1v += p*Vsv[k][1];
    }
    float inv = 1.0f/l;
    float* orow = o1 + (size_t)(blk*N1V + n)*MIDD + h*2;
    orow[0] = o0*inv; orow[1] = o1v*inv;
}

// fused: flat = o1 @ projw^T + projb + feat(d_out mapped); then segment-accumulate
__global__ __launch_bounds__(256) void k_flatseg(const float* __restrict__ o1, const float* __restrict__ Wp,
                                                 const float* __restrict__ bp, const float* __restrict__ outx,
                                                 const int* __restrict__ idx,
                                                 float* __restrict__ ssum, u32* __restrict__ smax,
                                                 int* __restrict__ scnt){
    int i = blockIdx.x; int tid = threadIdx.x;
    __shared__ float orow[MIDD];
    if (tid < MIDD) orow[tid] = o1[(size_t)i*MIDD + tid];
    __syncthreads();
    int sg = idx[i];
    if (tid == 0) atomicAdd(&scnt[sg], 1);
    size_t rb = (size_t)(i + (i>>9) + 1)*CDIM, sb = (size_t)sg*CDIM;
    for (int c=tid; c<CDIM; c+=256){
        const float* w = Wp + (size_t)c*MIDD;
        float a = bp[c];
        #pragma unroll
        for (int mm=0; mm<MIDD; mm++) a += orow[mm]*w[mm];
        a += outx[rb+c];
        atomicAdd(&ssum[sb+c], a);
        u32 u = __float_as_uint(a);
        u = (u & 0x80000000u) ? ~u : (u | 0x80000000u);
        atomicMax(&smax[sb+c], u);
    }
}

// cossim + sims-normalize + weighted sum + residual; block per token row; in-place on d_out
__global__ __launch_bounds__(256) void k_final(float* __restrict__ outx, const float* __restrict__ x3d,
                                               const bf16* __restrict__ bnv, const int* __restrict__ cluster,
                                               const int* __restrict__ fgi){
    int i = blockIdx.x; int tid = threadIdx.x;
    int cl = cluster[i];
    const float* xr = x3d + (size_t)cl*CDIM;
    const bf16* pr[NVIEW];
    #pragma unroll
    for (int v=0; v<NVIEW; v++)
        pr[v] = bnv + ((size_t)v*D1SEG + fgi[(size_t)v*NR + i])*CDIM;
    size_t rb = (size_t)(i + (i>>9) + 1)*CDIM;
    float pv[NVIEW][3], ft[3];
    float dotv[NVIEW] = {0,0,0,0,0,0};
    float np2[NVIEW]  = {0,0,0,0,0,0};
    float nx2 = 0.0f;
    #pragma unroll
    for (int j=0; j<3; j++){
        int c = tid + j*256;
        float xv = xr[c]; nx2 += xv*xv;
        ft[j] = outx[rb + c];
        #pragma unroll
        for (int v=0; v<NVIEW; v++){
            float p = b2f(pr[v][c]); pv[v][j] = p;
            dotv[v] += p*xv; np2[v] += p*p;
        }
    }
    __shared__ float part[4*13];
    __shared__ float ssim[NVIEW];
    float vals[13];
    vals[0] = nx2;
    #pragma unroll
    for (int v=0; v<NVIEW; v++){ vals[1+v] = dotv[v]; vals[7+v] = np2[v]; }
    int lane = tid & 63, wid = tid >> 6;
    #pragma unroll
    for (int k=0; k<13; k++){
        float w = vals[k];
        #pragma unroll
        for (int o=32;o;o>>=1) w += __shfl_down(w,o,64);
        if (!lane) part[wid*13 + k] = w;
    }
    __syncthreads();
    if (tid == 0){
        float tot[13];
        #pragma unroll
        for (int k=0; k<13; k++) tot[k] = part[k] + part[13+k] + part[26+k] + part[39+k];
        float nb = fmaxf(sqrtf(tot[0]), 1e-8f);
        float sv[NVIEW]; float ssumv = 0.0f;
        #pragma unroll
        for (int v=0; v<NVIEW; v++){
            float na = fmaxf(sqrtf(tot[7+v]), 1e-8f);
            float cs = tot[1+v] / (na*nb);
            sv[v] = (cs + 1.0f)*0.5f;
            ssumv += sv[v];
        }
        #pragma unroll
        for (int v=0; v<NVIEW; v++) ssim[v] = sv[v]/ssumv;
    }
    __syncthreads();
    #pragma unroll
    for (int j=0; j<3; j++){
        int c = tid + j*256;
        float xs = 0.0f;
        #pragma unroll
        for (int v=0; v<NVIEW; v++) xs += ssim[v]*pv[v][j];
        outx[rb + c] = ft[j] + 0.3f*xs;
    }
}

// ---------------- host launcher ----------------
extern "C" void kernel_launch(void* const* d_in, const int* in_sizes, int n_in,
                              void* d_out, int out_size, void* d_ws, size_t ws_size,
                              hipStream_t stream){
    const float* x     = (const float*)d_in[0];
    const float* ln1g  = (const float*)d_in[1];
    const float* ln1b  = (const float*)d_in[2];
    const float* ln2g  = (const float*)d_in[3];
    const float* ln2b  = (const float*)d_in[4];
    const float* Wqkv  = (const float*)d_in[5];
    const float* bqkv  = (const float*)d_in[6];
    const float* Wo    = (const float*)d_in[7];
    const float* bo    = (const float*)d_in[8];
    const float* Wfc   = (const float*)d_in[9];
    const float* bfc   = (const float*)d_in[10];
    const float* Wproj = (const float*)d_in[11];
    const float* bproj = (const float*)d_in[12];
    const float* Wa1   = (const float*)d_in[13];
    const float* ba1   = (const float*)d_in[14];
    const float* Wa2   = (const float*)d_in[15];
    const float* ba2   = (const float*)d_in[16];
    const float* bn3dg = (const float*)d_in[17];
    const float* bn3db = (const float*)d_in[18];
    const float* bn1dg = (const float*)d_in[19];
    const float* bn1db = (const float*)d_in[20];
    const float* n3g   = (const float*)d_in[21];
    const float* n3b   = (const float*)d_in[22];
    const float* aqw   = (const float*)d_in[23];
    const float* aqb   = (const float*)d_in[24];
    const float* apw   = (const float*)d_in[25];
    const float* apb   = (const float*)d_in[26];
    const int*   cluster = (const int*)d_in[27];
    const int*   fgi     = (const int*)d_in[28];
    const unsigned char* mask = (const unsigned char*)d_in[29];
    float* out = (float*)d_out;
    float* ws  = (float*)d_ws;

    bf16*  yb    = (bf16*)(ws + A_FS);       // y / obuf / y2 / yview
    bf16*  qkvb  = (bf16*)(ws + B_FS);
    bf16*  hb    = (bf16*)(ws + B_FS);       // FFN hidden chunk (qkv dead)
    bf16*  xffb  = (bf16*)(ws + B_FS + 6303744);
    float* qkv1  = ws + B_FS;                // phase 2 (all of B dead)
    float* o1    = ws + B_FS + 589824;
    float* svs   = ws + B_FS + 786432;
    bf16*  x1b   = (bf16*)(ws + X1_FS);
    float* ah    = ws + AH_FS;
    float* Dsum  = ws + D_FS;
    u32*   Dmax  = (u32*)(ws + DMAX_FS);
    int*   Dcnt  = (int*)(ws + DCNT_FS);
    float* x3d   = ws + X3D_FS;
    bf16*  bnv   = (bf16*)(ws + BNV_FS);
    float* statm = ws + STATM_FS;
    float* statr = ws + STATR_FS;
    // bf16 weights live in D region during phase 1 (D scratch first used at step 10)
    bf16* WqkvB  = (bf16*)(ws + D_FS);
    bf16* WoB    = WqkvB + 2304*768;
    bf16* WfcB   = WoB   + 768*768;
    bf16* WprojB = WfcB  + 3072*768;

    // 0. weight conversion fp32 -> bf16
    k_f2b<<<1024, 256, 0, stream>>>(Wqkv,  WqkvB,  2304*768);
    k_f2b<<<1024, 256, 0, stream>>>(Wo,    WoB,    768*768);
    k_f2b<<<1024, 256, 0, stream>>>(Wfc,   WfcB,   3072*768);
    k_f2b<<<1024, 256, 0, stream>>>(Wproj, WprojB, 768*3072);
    // 1. LN1 (x fp32 -> y bf16)
    k_ln<float,false><<<NT, 256, 0, stream>>>(x, yb, ln1g, ln1b);
    // 2. qkv GEMM (MFMA, bf16 out)
    k_gemm_mfma<bf16,0,0><<<dim3(2304/128, (NT+127)/128), 256, 0, stream>>>(yb, WqkvB, bqkv, nullptr, qkvb, NT, 2304, 768);
    // 3. flash MFMA attention -> obuf (A region; y dead)
    k_attn_mfma<<<dim3(9, NHEAD, BATCH), 256, 0, stream>>>(qkvb, yb);
    // 4. o-proj + residual(x) -> x1 bf16
    k_gemm_mfma<bf16,0,1><<<dim3(768/128, (NT+127)/128), 256, 0, stream>>>(yb, WoB, bo, x, x1b, NT, 768, 768);
    // 5. LN2 (x1 bf16 -> y2 bf16 in A)
    k_ln<bf16,false><<<NT, 256, 0, stream>>>(x1b, yb, ln2g, ln2b);
    // 6/7. FFN in 4 row-chunks (h chunk in B; qkv dead)
    for (int cch=0; cch<4; cch++){
        const bf16* a2 = yb + (size_t)cch*CHROWS*CDIM;
        bf16* xo = xffb + (size_t)cch*CHROWS*CDIM;
        k_gemm_mfma<bf16,1,0><<<dim3(FFDIM/128, (CHROWS+127)/128), 256, 0, stream>>>(a2, WfcB, bfc, nullptr, hb, CHROWS, FFDIM, 768);
        k_gemm_mfma<bf16,0,0><<<dim3(768/128, (CHROWS+127)/128), 256, 0, stream>>>(hb, WprojB, bproj, nullptr, xo, CHROWS, 768, FFDIM);
    }
    // 8. adapt hidden (fp32 out, quick_gelu) — small N, scalar path
    k_gemm<float,1><<<dim3(1, (NT+TM-1)/TM), 256, 0, stream>>>(xffb, Wa1, ba1, ah, NT, 16, 768);
    // 9. combine -> d_out (x2; cls rows final)
    k_comb<<<NT, 256, 0, stream>>>(x1b, xffb, ah, Wa2, ba2, out);
    // 10. cluster segment max/mean + bn_gelu -> x3d
    k_zero<<<4096, 256, 0, stream>>>(Dsum, DTOT_FS);
    k_segacc<<<NR, 256, 0, stream>>>(out, cluster, Dsum, Dmax, Dcnt);
    k_segcomb<<<(NCLUST*CDIM+255)/256, 256, 0, stream>>>(Dsum, Dmax, Dcnt, x3d, NCLUST*CDIM);
    k_zero<<<6, 256, 0, stream>>>(statm, 1536);
    k_colstats_part<<<dim3(3, 32), 256, 0, stream>>>(x3d, NCLUST, statm, statr);
    k_colfin<<<3, 256, 0, stream>>>(statm, statr, NCLUST);
    k_bngelu<float><<<(NCLUST*CDIM+255)/256, 256, 0, stream>>>(x3d, x3d, statm, statr, bn3dg, bn3db, NCLUST*CDIM);
    // 11. views
    for (int v=0; v<NVIEW; v++){
        k_ln<float,true><<<NR, 256, 0, stream>>>(out, yb, n3g + v*CDIM, n3b + v*CDIM);
        k_gemm<float,0><<<dim3(1, NR/TM), 256, 0, stream>>>(yb, aqw + (size_t)v*36*768, aqb + v*36, qkv1, NR, 36, 768);
        k_attnv<<<dim3(NB1, H1N), 128, 0, stream>>>(qkv1, mask + (size_t)v*NB1*N1V*N1V, o1);
        k_zero<<<4096, 256, 0, stream>>>(Dsum, DTOT_FS);
        k_flatseg<<<NR, 256, 0, stream>>>(o1, apw + (size_t)v*CDIM*MIDD, apb + v*CDIM, out,
                                          fgi + (size_t)v*NR, Dsum, Dmax, Dcnt);
        k_segcomb<<<(D1SEG*CDIM+255)/256, 256, 0, stream>>>(Dsum, Dmax, Dcnt, svs, D1SEG*CDIM);
        k_zero<<<6, 256, 0, stream>>>(statm, 1536);
        k_colstats_part<<<dim3(3, 32), 256, 0, stream>>>(svs, D1SEG, statm, statr);
        k_colfin<<<3, 256, 0, stream>>>(statm, statr, D1SEG);
        k_bngelu<bf16><<<(D1SEG*CDIM+255)/256, 256, 0, stream>>>(svs, bnv + (size_t)v*D1SEG*CDIM, statm, statr,
                                                                 bn1dg + v*CDIM, bn1db + v*CDIM, D1SEG*CDIM);
    }
    // 12. final combine (in-place on d_out)
    k_final<<<NR, 256, 0, stream>>>(out, x3d, bnv, cluster, fgi);
}

// Round 5
// 2165.831 us; speedup vs baseline: 9.8193x; 1.4231x over previous
//
#include <hip/hip_runtime.h>
#include <hip/hip_bf16.h>
#include <math.h>

typedef unsigned int u32;
typedef __hip_bfloat16 bf16;
typedef __attribute__((ext_vector_type(8))) short bh8;
typedef __attribute__((ext_vector_type(4))) float fx4;

#define CDIM   768
#define BATCH  32
#define SEQ    513
#define NT     (BATCH*SEQ)     // 16416 rows incl cls
#define NR     16384           // BG
#define NHEAD  12
#define HD     64
#define FFDIM  3072
#define NCLUST 2048
#define D1SEG  6272
#define NVIEW  6
#define MIDD   12
#define H1N    6
#define N1V    128
#define NB1    128
#define CHROWS 4104            // FFN row chunk (4 chunks)

// ---------------- workspace layout (float-slot offsets; ≈229.8 MB total) ----
#define A_FS      ((size_t)0)          // 6,303,744 fs : y / obuf / y2 / yv  (NT*768 bf16)
#define B_FS      ((size_t)6303744)    // 18,911,232 fs: qkv bf16 | h+xffn bf16 | qkv1a+o1all+svs
#define X1_FS     ((size_t)25214976)   // 6,303,744 fs : x1 bf16
#define AH_FS     ((size_t)31518720)   // 262,656 fs   : ah fp32
#define D_FS      ((size_t)31781376)   // 9,640,064 fs : index arrays | bf16 weights
#define DTOT_FS   9640064
#define X3D_FS    ((size_t)(D_FS + DTOT_FS))          // 1,572,864 fs x3d fp32
#define BNV_FS    (X3D_FS + 1572864)                  // 14,450,688 fs bnv bf16
#define STATM_FS  (BNV_FS + 14450688)                 // 768
#define STATR_FS  (STATM_FS + 768)                    // 768
// D region internal layout:
//   +0        : icnt (6272 i32), ibase(6272), icur(6272), order(16384)  -> 35,200 fs  [phase >=10]
//   +40960    : WqkvB/WoB/WfcB/WprojB bf16 = 3,538,944 fs               [phase 1-7]
//   +3600000  : WvB (82,944 fs) , bvP (216 fs), Wa1B (6,144 fs)         [all phases]
#define DI_CNT    (D_FS)
#define DI_BASE   (D_FS + 6272)
#define DI_CUR    (D_FS + 12544)
#define DI_ORD    (D_FS + 18816)
#define DW_FS     (D_FS + 40960)
#define DWV_FS    (D_FS + 3600000)

__device__ inline float b2f(bf16 v){ return __bfloat162float(v); }
__device__ inline float ldv(const float* p, size_t i){ return p[i]; }
__device__ inline float ldv(const bf16*  p, size_t i){ return __bfloat162float(p[i]); }
__device__ inline void  stv(float* p, size_t i, float v){ p[i] = v; }
__device__ inline void  stv(bf16*  p, size_t i, float v){ p[i] = __float2bfloat16(v); }
__device__ inline short f2bs(float f){ bf16 h = __float2bfloat16(f); return *(short*)&h; }

// ---------------- utility ----------------

__global__ __launch_bounds__(256) void k_zero(float* p, int n){
    for (int i = blockIdx.x*256 + threadIdx.x; i < n; i += gridDim.x*256) p[i] = 0.0f;
}

__global__ __launch_bounds__(256) void k_f2b(const float* __restrict__ in, bf16* __restrict__ out, int n){
    for (int i = blockIdx.x*256 + threadIdx.x; i < n; i += gridDim.x*256)
        out[i] = __float2bfloat16(in[i]);
}

// LayerNorm over C=768, one block per row; out bf16
template<typename TI>
__global__ __launch_bounds__(256) void k_ln(const TI* __restrict__ in, bf16* __restrict__ out,
                                            const float* __restrict__ g, const float* __restrict__ b){
    int i = blockIdx.x;
    int tid = threadIdx.x;
    const TI* r = in + (size_t)i*CDIM;
    float v0 = ldv(r,(size_t)tid), v1 = ldv(r,(size_t)tid+256), v2 = ldv(r,(size_t)tid+512);
    float s  = v0+v1+v2;
    float s2 = v0*v0+v1*v1+v2*v2;
    __shared__ float t1[4], t2[4];
    #pragma unroll
    for (int o=32;o;o>>=1){ s += __shfl_down(s,o,64); s2 += __shfl_down(s2,o,64); }
    int lane = tid & 63, wid = tid >> 6;
    if (!lane){ t1[wid]=s; t2[wid]=s2; }
    __syncthreads();
    float S  = t1[0]+t1[1]+t1[2]+t1[3];
    float S2 = t2[0]+t2[1]+t2[2]+t2[3];
    float m  = S * (1.0f/CDIM);
    float var = S2 * (1.0f/CDIM) - m*m;
    float rstd = rsqrtf(var + 1e-5f);
    bf16* o_ = out + (size_t)i*CDIM;
    stv(o_,(size_t)tid,     (v0-m)*rstd*g[tid]     + b[tid]);
    stv(o_,(size_t)tid+256, (v1-m)*rstd*g[tid+256] + b[tid+256]);
    stv(o_,(size_t)tid+512, (v2-m)*rstd*g[tid+512] + b[tid+512]);
}

// normalize-only LN (affine folded into downstream weights), token-row map on input
__global__ __launch_bounds__(256) void k_lnn(const float* __restrict__ in, bf16* __restrict__ out){
    int i = blockIdx.x;
    size_t ri = (size_t)(i + (i>>9) + 1);
    int tid = threadIdx.x;
    const float* r = in + ri*CDIM;
    float v0 = r[tid], v1 = r[tid+256], v2 = r[tid+512];
    float s  = v0+v1+v2;
    float s2 = v0*v0+v1*v1+v2*v2;
    __shared__ float t1[4], t2[4];
    #pragma unroll
    for (int o=32;o;o>>=1){ s += __shfl_down(s,o,64); s2 += __shfl_down(s2,o,64); }
    int lane = tid & 63, wid = tid >> 6;
    if (!lane){ t1[wid]=s; t2[wid]=s2; }
    __syncthreads();
    float S  = t1[0]+t1[1]+t1[2]+t1[3];
    float S2 = t2[0]+t2[1]+t2[2]+t2[3];
    float m  = S * (1.0f/CDIM);
    float var = S2 * (1.0f/CDIM) - m*m;
    float rstd = rsqrtf(var + 1e-5f);
    bf16* o_ = out + (size_t)i*CDIM;
    stv(o_,(size_t)tid,     (v0-m)*rstd);
    stv(o_,(size_t)tid+256, (v1-m)*rstd);
    stv(o_,(size_t)tid+512, (v2-m)*rstd);
}

// fold per-view LN affine into view-qkv weights: W'[row,k]=W*g ; b'[row]=aqb+Σ W*b
__global__ __launch_bounds__(256) void k_foldw(const float* __restrict__ aqw, const float* __restrict__ aqb,
                                               const float* __restrict__ n3g, const float* __restrict__ n3b,
                                               bf16* __restrict__ Wv, float* __restrict__ bv){
    int row = blockIdx.x;                  // 0..215
    int v = row/36;
    const float* w = aqw + (size_t)row*768;
    const float* g = n3g + v*768;
    const float* b = n3b + v*768;
    int tid = threadIdx.x;
    float s = 0.0f;
    #pragma unroll
    for (int j=tid; j<768; j+=256){
        float wv = w[j];
        Wv[(size_t)row*768 + j] = __float2bfloat16(wv*g[j]);
        s += wv*b[j];
    }
    __shared__ float t1[4];
    #pragma unroll
    for (int o=32;o;o>>=1) s += __shfl_down(s,o,64);
    int lane = tid & 63, wid = tid >> 6;
    if (!lane) t1[wid]=s;
    __syncthreads();
    if (tid==0) bv[row] = aqb[row] + t1[0]+t1[1]+t1[2]+t1[3];
}

// ---------------- MFMA GEMM: out[M,N] = A[M,K](bf16) @ W[N,K]^T(bf16) + bias ----------------
#define GSTR 40
template<typename TO, int ACT, int RES>
__global__ __launch_bounds__(256) void k_gemm_mfma(const bf16* __restrict__ A, const bf16* __restrict__ W,
                                                   const float* __restrict__ bias, const float* __restrict__ res,
                                                   TO* __restrict__ out, int M, int N, int K){
    __shared__ short As[128*GSTR];
    __shared__ short Ws[128*GSTR];
    int bm = blockIdx.y*128, bn = blockIdx.x*128;
    int tid = threadIdx.x, wid = tid>>6, lane = tid&63, quad = lane>>4, l16 = lane&15;
    int wr = (wid>>1)*64, wc = (wid&1)*64;
    fx4 acc[4][4];
    #pragma unroll
    for (int i=0;i<4;i++)
        #pragma unroll
        for (int j=0;j<4;j++) acc[i][j] = (fx4){0.f,0.f,0.f,0.f};
    int sr = tid>>1, sc0 = (tid&1)*16;
    bool aval = (bm+sr) < M;
    bool wval = (bn+sr) < N;
    const bf16* arow = A + (size_t)(aval ? bm+sr : 0)*K;
    const bf16* wrow = W + (size_t)(wval ? bn+sr : 0)*K;
    const bh8 zv = {0,0,0,0,0,0,0,0};
    for (int k0=0; k0<K; k0+=32){
        bh8 a0 = aval ? *(const bh8*)(arow + k0 + sc0)     : zv;
        bh8 a1 = aval ? *(const bh8*)(arow + k0 + sc0 + 8) : zv;
        bh8 w0 = wval ? *(const bh8*)(wrow + k0 + sc0)     : zv;
        bh8 w1 = wval ? *(const bh8*)(wrow + k0 + sc0 + 8) : zv;
        *(bh8*)&As[sr*GSTR + sc0]     = a0;
        *(bh8*)&As[sr*GSTR + sc0 + 8] = a1;
        *(bh8*)&Ws[sr*GSTR + sc0]     = w0;
        *(bh8*)&Ws[sr*GSTR + sc0 + 8] = w1;
        __syncthreads();
        bh8 af[4], bf_[4];
        #pragma unroll
        for (int i=0;i<4;i++) af[i]  = *(const bh8*)&As[(wr + i*16 + l16)*GSTR + quad*8];
        #pragma unroll
        for (int j=0;j<4;j++) bf_[j] = *(const bh8*)&Ws[(wc + j*16 + l16)*GSTR + quad*8];
        #pragma unroll
        for (int i=0;i<4;i++)
            #pragma unroll
            for (int j=0;j<4;j++)
                acc[i][j] = __builtin_amdgcn_mfma_f32_16x16x32_bf16(af[i], bf_[j], acc[i][j], 0,0,0);
        __syncthreads();
    }
    #pragma unroll
    for (int i=0;i<4;i++){
        #pragma unroll
        for (int r=0;r<4;r++){
            int row = bm + wr + i*16 + quad*4 + r;
            if (row >= M) continue;
            #pragma unroll
            for (int j=0;j<4;j++){
                int col = bn + wc + j*16 + l16;
                if (col >= N) continue;
                float v = acc[i][j][r] + bias[col];
                if (ACT == 1) v = v / (1.0f + __expf(-1.702f*v));
                if (RES) v += res[(size_t)row*N + col];
                stv(out, (size_t)row*N + col, v);
            }
        }
    }
}

// ---------------- flash MFMA attention: block per (qtile, h, b) ----------------
#define KSTR 72
__global__ __launch_bounds__(256) void k_attn_mfma(const bf16* __restrict__ qkv, bf16* __restrict__ obuf){
    __shared__ short Ks[64*KSTR];      // [k][d]
    __shared__ short Vt[64*KSTR];      // [d][k]  (transposed)
    __shared__ short Ps[4*16*KSTR];    // per-wave P strip [16 q][64 k]
    int qt = blockIdx.x, h = blockIdx.y, b = blockIdx.z;
    int tid = threadIdx.x, wid = tid>>6, lane = tid&63, quad = lane>>4, l16 = lane&15;
    size_t base = (size_t)b*SEQ*2304;
    int q_own = qt*64 + wid*16 + l16;
    int q_cl  = q_own > 512 ? 512 : q_own;
    const bf16* qrow = qkv + base + (size_t)q_cl*2304 + h*HD;
    bh8 qa0 = *(const bh8*)(qrow + quad*8);
    bh8 qa1 = *(const bh8*)(qrow + 32 + quad*8);
    fx4 o[4];
    #pragma unroll
    for (int d=0; d<4; d++) o[d] = (fx4){0.f,0.f,0.f,0.f};
    float mrow[4] = {-1e30f,-1e30f,-1e30f,-1e30f};
    float lrow[4] = {0.f,0.f,0.f,0.f};
    int srow = tid>>2, d0 = (tid&3)*16;
    for (int kt=0; kt<9; kt++){
        int kg = kt*64 + srow;
        if (kg < SEQ){
            const bf16* krow = qkv + base + 768  + (size_t)kg*2304 + h*HD;
            const bf16* vrow = qkv + base + 1536 + (size_t)kg*2304 + h*HD;
            bh8 kv0 = *(const bh8*)(krow + d0);
            bh8 kv1 = *(const bh8*)(krow + d0 + 8);
            bh8 vv0 = *(const bh8*)(vrow + d0);
            bh8 vv1 = *(const bh8*)(vrow + d0 + 8);
            *(bh8*)&Ks[srow*KSTR + d0]     = kv0;
            *(bh8*)&Ks[srow*KSTR + d0 + 8] = kv1;
            #pragma unroll
            for (int j=0;j<8;j++){ Vt[(d0+j)*KSTR + srow] = vv0[j]; Vt[(d0+8+j)*KSTR + srow] = vv1[j]; }
        } else {
            const bh8 zv = {0,0,0,0,0,0,0,0};
            *(bh8*)&Ks[srow*KSTR + d0]     = zv;
            *(bh8*)&Ks[srow*KSTR + d0 + 8] = zv;
            #pragma unroll
            for (int j=0;j<16;j++) Vt[(d0+j)*KSTR + srow] = 0;
        }
        __syncthreads();
        fx4 s[4];
        #pragma unroll
        for (int nt=0; nt<4; nt++){
            bh8 kb0 = *(const bh8*)&Ks[(nt*16+l16)*KSTR + quad*8];
            bh8 kb1 = *(const bh8*)&Ks[(nt*16+l16)*KSTR + 32 + quad*8];
            fx4 a = (fx4){0.f,0.f,0.f,0.f};
            a = __builtin_amdgcn_mfma_f32_16x16x32_bf16(qa0, kb0, a, 0,0,0);
            a = __builtin_amdgcn_mfma_f32_16x16x32_bf16(qa1, kb1, a, 0,0,0);
            s[nt] = a;
        }
        float tmax[4] = {-1e30f,-1e30f,-1e30f,-1e30f};
        #pragma unroll
        for (int nt=0; nt<4; nt++){
            bool ok = (kt*64 + nt*16 + l16) <= 512;
            #pragma unroll
            for (int r=0;r<4;r++){
                float v = ok ? s[nt][r]*0.125f : -1e30f;
                s[nt][r] = v;
                tmax[r] = fmaxf(tmax[r], v);
            }
        }
        #pragma unroll
        for (int msk=1; msk<16; msk<<=1)
            #pragma unroll
            for (int r=0;r<4;r++) tmax[r] = fmaxf(tmax[r], __shfl_xor(tmax[r], msk, 64));
        float al[4];
        #pragma unroll
        for (int r=0;r<4;r++){
            float mn = fmaxf(mrow[r], tmax[r]);
            al[r] = __expf(mrow[r] - mn);
            mrow[r] = mn;
        }
        float ps[4] = {0.f,0.f,0.f,0.f};
        #pragma unroll
        for (int nt=0; nt<4; nt++)
            #pragma unroll
            for (int r=0;r<4;r++){
                float p = __expf(s[nt][r] - mrow[r]);
                s[nt][r] = p;
                ps[r] += p;
            }
        #pragma unroll
        for (int msk=1; msk<16; msk<<=1)
            #pragma unroll
            for (int r=0;r<4;r++) ps[r] += __shfl_xor(ps[r], msk, 64);
        #pragma unroll
        for (int r=0;r<4;r++){
            lrow[r] = lrow[r]*al[r] + ps[r];
            #pragma unroll
            for (int d=0; d<4; d++) o[d][r] *= al[r];
        }
        #pragma unroll
        for (int nt=0; nt<4; nt++)
            #pragma unroll
            for (int r=0;r<4;r++)
                Ps[(wid*16 + quad*4 + r)*KSTR + nt*16 + l16] = f2bs(s[nt][r]);
        bh8 pa0 = *(const bh8*)&Ps[(wid*16 + l16)*KSTR + quad*8];
        bh8 pa1 = *(const bh8*)&Ps[(wid*16 + l16)*KSTR + 32 + quad*8];
        #pragma unroll
        for (int dt=0; dt<4; dt++){
            bh8 vb0 = *(const bh8*)&Vt[(dt*16+l16)*KSTR + quad*8];
            bh8 vb1 = *(const bh8*)&Vt[(dt*16+l16)*KSTR + 32 + quad*8];
            o[dt] = __builtin_amdgcn_mfma_f32_16x16x32_bf16(pa0, vb0, o[dt], 0,0,0);
            o[dt] = __builtin_amdgcn_mfma_f32_16x16x32_bf16(pa1, vb1, o[dt], 0,0,0);
        }
        __syncthreads();
    }
    float inv[4];
    #pragma unroll
    for (int r=0;r<4;r++) inv[r] = 1.0f/lrow[r];
    #pragma unroll
    for (int r=0;r<4;r++){
        int q = qt*64 + wid*16 + quad*4 + r;
        if (q < SEQ){
            size_t ob = ((size_t)(b*SEQ+q))*CDIM + h*HD;
            #pragma unroll
            for (int dt=0; dt<4; dt++)
                obuf[ob + dt*16 + l16] = __float2bfloat16(o[dt][r]*inv[r]);
        }
    }
}

// x2 = x1 + xffn + 0.5*(ah @ Wa2^T + ba2) -> d_out (fp32); block per row
__global__ __launch_bounds__(256) void k_comb(const bf16* __restrict__ x1, const bf16* __restrict__ xffn,
                                              const float* __restrict__ ah, const float* __restrict__ Wa2,
                                              const float* __restrict__ ba2, float* __restrict__ x2){
    int i = blockIdx.x; int tid = threadIdx.x;
    __shared__ float ar[16];
    if (tid < 16) ar[tid] = ah[(size_t)i*16 + tid];
    __syncthreads();
    for (int c=tid; c<CDIM; c+=256){
        const float* w = Wa2 + (size_t)c*16;
        float a = ba2[c];
        #pragma unroll
        for (int mm=0; mm<16; mm++) a += ar[mm]*w[mm];
        size_t o = (size_t)i*CDIM + c;
        x2[o] = b2f(x1[o]) + b2f(xffn[o]) + 0.5f*a;
    }
}

// ---------------- segment index build ----------------
__global__ __launch_bounds__(256) void k_icount(const int* __restrict__ idx, int* __restrict__ cnt, int n){
    int i = blockIdx.x*256 + threadIdx.x;
    if (i < n) atomicAdd(&cnt[idx[i]], 1);
}

__global__ __launch_bounds__(256) void k_iscan(const int* __restrict__ cnt, int* __restrict__ base,
                                               int* __restrict__ cur, int nseg){
    __shared__ int part[256], off[256];
    int t = threadIdx.x;
    int chunk = (nseg + 255) >> 8;
    int j0 = t*chunk, j1 = j0 + chunk; if (j1 > nseg) j1 = nseg;
    int s = 0;
    for (int j=j0; j<j1; j++) s += cnt[j];
    part[t] = s; __syncthreads();
    if (t == 0){ int acc=0; for (int i=0;i<256;i++){ off[i]=acc; acc+=part[i]; } }
    __syncthreads();
    int acc = off[t];
    for (int j=j0; j<j1; j++){ base[j]=acc; cur[j]=acc; acc+=cnt[j]; }
}

__global__ __launch_bounds__(256) void k_iscatter(const int* __restrict__ idx, int* __restrict__ cur,
                                                  int* __restrict__ order, int n){
    int i = blockIdx.x*256 + threadIdx.x;
    if (i < n){
        int pos = atomicAdd(&cur[idx[i]], 1);
        order[pos] = i;
    }
}

// gather + segment max/mean for cluster path: dst[sg] = smax + smean, block per segment
__global__ __launch_bounds__(256) void k_gather_seg(const float* __restrict__ outx, const int* __restrict__ basep,
                                                    const int* __restrict__ cntp, const int* __restrict__ order,
                                                    float* __restrict__ dst){
    int sg = blockIdx.x; int tid = threadIdx.x;
    int n = cntp[sg], b0 = basep[sg];
    float mx[3] = {-1e30f,-1e30f,-1e30f};
    float sm[3] = {0.f,0.f,0.f};
    for (int r=0; r<n; r++){
        int i = order[b0+r];
        size_t rb = (size_t)(i + (i>>9) + 1)*CDIM;
        #pragma unroll
        for (int j=0;j<3;j++){
            float v = outx[rb + tid + j*256];
            mx[j] = fmaxf(mx[j], v); sm[j] += v;
        }
    }
    float den = (float)(n > 1 ? n : 1);
    size_t db = (size_t)sg*CDIM;
    #pragma unroll
    for (int j=0;j<3;j++)
        dst[db + tid + j*256] = (n > 0 ? mx[j] : 0.f) + sm[j]/den;
}

// per-view: flat = o1@Wp^T + bp + feat, then segment max/mean; block per segment
__global__ __launch_bounds__(256) void k_gather_flat(const float* __restrict__ outx, const float* __restrict__ o1v,
                                                     const float* __restrict__ Wp, const float* __restrict__ bp,
                                                     const int* __restrict__ basep, const int* __restrict__ cntp,
                                                     const int* __restrict__ order, float* __restrict__ dst){
    int sg = blockIdx.x; int tid = threadIdx.x;
    int n = cntp[sg], b0 = basep[sg];
    float w[3][MIDD], bb[3];
    #pragma unroll
    for (int j=0;j<3;j++){
        int c = tid + j*256;
        bb[j] = bp[c];
        #pragma unroll
        for (int mm=0;mm<MIDD;mm++) w[j][mm] = Wp[(size_t)c*MIDD + mm];
    }
    float mx[3] = {-1e30f,-1e30f,-1e30f};
    float sm[3] = {0.f,0.f,0.f};
    for (int r=0; r<n; r++){
        int i = order[b0+r];
        const float* orow = o1v + (size_t)i*MIDD;
        float ov[MIDD];
        #pragma unroll
        for (int mm=0;mm<MIDD;mm++) ov[mm] = orow[mm];
        size_t rb = (size_t)(i + (i>>9) + 1)*CDIM;
        #pragma unroll
        for (int j=0;j<3;j++){
            float a = bb[j];
            #pragma unroll
            for (int mm=0;mm<MIDD;mm++) a += ov[mm]*w[j][mm];
            a += outx[rb + tid + j*256];
            mx[j] = fmaxf(mx[j], a); sm[j] += a;
        }
    }
    float den = (float)(n > 1 ? n : 1);
    size_t db = (size_t)sg*CDIM;
    #pragma unroll
    for (int j=0;j<3;j++)
        dst[db + tid + j*256] = (n > 0 ? mx[j] : 0.f) + sm[j]/den;
}

// two-stage column stats
__global__ __launch_bounds__(256) void k_colstats_part(const float* __restrict__ in, int rows,
                                                       float* __restrict__ sumv, float* __restrict__ sumsq){
    int c = blockIdx.x*256 + threadIdx.x;
    if (c >= CDIM) return;
    int chunk = (rows + 31) >> 5;
    int r0 = blockIdx.y*chunk;
    int r1 = r0 + chunk; if (r1 > rows) r1 = rows;
    float s = 0.0f, s2 = 0.0f;
    for (int r=r0; r<r1; r++){
        float v = in[(size_t)r*CDIM + c];
        s += v; s2 += v*v;
    }
    atomicAdd(&sumv[c], s);
    atomicAdd(&sumsq[c], s2);
}

__global__ __launch_bounds__(256) void k_colfin(float* __restrict__ sumv, float* __restrict__ sumsq, int rows){
    int c = blockIdx.x*256 + threadIdx.x;
    if (c >= CDIM) return;
    float m = sumv[c] / (float)rows;
    float var = sumsq[c] / (float)rows - m*m;
    sumv[c]  = m;
    sumsq[c] = rsqrtf(fmaxf(var, 0.0f) + 1e-5f);
}

template<typename TO>
__global__ __launch_bounds__(256) void k_bngelu(const float* __restrict__ in, TO* __restrict__ outp,
                                                const float* __restrict__ m, const float* __restrict__ r,
                                                const float* __restrict__ g, const float* __restrict__ b, int n){
    int i = blockIdx.x*256 + threadIdx.x;
    if (i >= n) return;
    int c = i - (i/CDIM)*CDIM;
    float y = (in[i]-m[c])*r[c]*g[c] + b[c];
    stv(outp, (size_t)i, 0.5f*y*(1.0f + erff(y*0.70710678118654752f)));
}

// per-view micro attention, all views batched: block per (segblock, head, view)
__global__ __launch_bounds__(128) void k_attnv(const float* __restrict__ qkv1a,
                                               const unsigned char* __restrict__ mask,
                                               float* __restrict__ o1all){
    int blk = blockIdx.x, h = blockIdx.y, v = blockIdx.z;
    int n = threadIdx.x;
    __shared__ float Ksv[N1V][2], Vsv[N1V][2];
    const float* rowp = qkv1a + (size_t)(blk*N1V + n)*216 + v*36;
    float q0 = rowp[h*2+0], q1 = rowp[h*2+1];
    Ksv[n][0] = rowp[12 + h*2 + 0]; Ksv[n][1] = rowp[12 + h*2 + 1];
    Vsv[n][0] = rowp[24 + h*2 + 0]; Vsv[n][1] = rowp[24 + h*2 + 1];
    __syncthreads();
    const unsigned char* mrow = mask + (((size_t)v*NB1 + blk)*N1V + n)*N1V;
    const float scale = 0.28867513459481287f; // 12^-0.5
    float m = -1e30f;
    for (int k=0; k<N1V; k++){
        float s = (q0*Ksv[k][0] + q1*Ksv[k][1])*scale + (mrow[k] ? -100000.0f : 0.0f);
        m = fmaxf(m, s);
    }
    float l = 0.0f, o0 = 0.0f, o1v = 0.0f;
    for (int k=0; k<N1V; k++){
        float s = (q0*Ksv[k][0] + q1*Ksv[k][1])*scale + (mrow[k] ? -100000.0f : 0.0f);
        float p = __expf(s - m);
        l += p; o0 += p*Vsv[k][0]; o1v += p*Vsv[k][1];
    }
    float inv = 1.0f/l;
    float* orow = o1all + ((size_t)v*NR + blk*N1V + n)*MIDD + h*2;
    orow[0] = o0*inv; orow[1] = o1v*inv;
}

// cossim + sims-normalize + weighted sum + residual; block per token row; in-place on d_out
__global__ __launch_bounds__(256) void k_final(float* __restrict__ outx, const float* __restrict__ x3d,
                                               const bf16* __restrict__ bnv, const int* __restrict__ cluster,
                                               const int* __restrict__ fgi){
    int i = blockIdx.x; int tid = threadIdx.x;
    int cl = cluster[i];
    const float* xr = x3d + (size_t)cl*CDIM;
    const bf16* pr[NVIEW];
    #pragma unroll
    for (int v=0; v<NVIEW; v++)
        pr[v] = bnv + ((size_t)v*D1SEG + fgi[(size_t)v*NR + i])*CDIM;
    size_t rb = (size_t)(i + (i>>9) + 1)*CDIM;
    float pv[NVIEW][3], ft[3];
    float dotv[NVIEW] = {0,0,0,0,0,0};
    float np2[NVIEW]  = {0,0,0,0,0,0};
    float nx2 = 0.0f;
    #pragma unroll
    for (int j=0; j<3; j++){
        int c = tid + j*256;
        float xv = xr[c]; nx2 += xv*xv;
        ft[j] = outx[rb + c];
        #pragma unroll
        for (int v=0; v<NVIEW; v++){
            float p = b2f(pr[v][c]); pv[v][j] = p;
            dotv[v] += p*xv; np2[v] += p*p;
        }
    }
    __shared__ float part[4*13];
    __shared__ float ssim[NVIEW];
    float vals[13];
    vals[0] = nx2;
    #pragma unroll
    for (int v=0; v<NVIEW; v++){ vals[1+v] = dotv[v]; vals[7+v] = np2[v]; }
    int lane = tid & 63, wid = tid >> 6;
    #pragma unroll
    for (int k=0; k<13; k++){
        float w = vals[k];
        #pragma unroll
        for (int o=32;o;o>>=1) w += __shfl_down(w,o,64);
        if (!lane) part[wid*13 + k] = w;
    }
    __syncthreads();
    if (tid == 0){
        float tot[13];
        #pragma unroll
        for (int k=0; k<13; k++) tot[k] = part[k] + part[13+k] + part[26+k] + part[39+k];
        float nb = fmaxf(sqrtf(tot[0]), 1e-8f);
        float sv[NVIEW]; float ssumv = 0.0f;
        #pragma unroll
        for (int v=0; v<NVIEW; v++){
            float na = fmaxf(sqrtf(tot[7+v]), 1e-8f);
            float cs = tot[1+v] / (na*nb);
            sv[v] = (cs + 1.0f)*0.5f;
            ssumv += sv[v];
        }
        #pragma unroll
        for (int v=0; v<NVIEW; v++) ssim[v] = sv[v]/ssumv;
    }
    __syncthreads();
    #pragma unroll
    for (int j=0; j<3; j++){
        int c = tid + j*256;
        float xs = 0.0f;
        #pragma unroll
        for (int v=0; v<NVIEW; v++) xs += ssim[v]*pv[v][j];
        outx[rb + c] = ft[j] + 0.3f*xs;
    }
}

// ---------------- host launcher ----------------
extern "C" void kernel_launch(void* const* d_in, const int* in_sizes, int n_in,
                              void* d_out, int out_size, void* d_ws, size_t ws_size,
                              hipStream_t stream){
    const float* x     = (const float*)d_in[0];
    const float* ln1g  = (const float*)d_in[1];
    const float* ln1b  = (const float*)d_in[2];
    const float* ln2g  = (const float*)d_in[3];
    const float* ln2b  = (const float*)d_in[4];
    const float* Wqkv  = (const float*)d_in[5];
    const float* bqkv  = (const float*)d_in[6];
    const float* Wo    = (const float*)d_in[7];
    const float* bo    = (const float*)d_in[8];
    const float* Wfc   = (const float*)d_in[9];
    const float* bfc   = (const float*)d_in[10];
    const float* Wproj = (const float*)d_in[11];
    const float* bproj = (const float*)d_in[12];
    const float* Wa1   = (const float*)d_in[13];
    const float* ba1   = (const float*)d_in[14];
    const float* Wa2   = (const float*)d_in[15];
    const float* ba2   = (const float*)d_in[16];
    const float* bn3dg = (const float*)d_in[17];
    const float* bn3db = (const float*)d_in[18];
    const float* bn1dg = (const float*)d_in[19];
    const float* bn1db = (const float*)d_in[20];
    const float* n3g   = (const float*)d_in[21];
    const float* n3b   = (const float*)d_in[22];
    const float* aqw   = (const float*)d_in[23];
    const float* aqb   = (const float*)d_in[24];
    const float* apw   = (const float*)d_in[25];
    const float* apb   = (const float*)d_in[26];
    const int*   cluster = (const int*)d_in[27];
    const int*   fgi     = (const int*)d_in[28];
    const unsigned char* mask = (const unsigned char*)d_in[29];
    float* out = (float*)d_out;
    float* ws  = (float*)d_ws;

    bf16*  yb    = (bf16*)(ws + A_FS);       // y / obuf / y2 / yv
    bf16*  qkvb  = (bf16*)(ws + B_FS);
    bf16*  hb    = (bf16*)(ws + B_FS);       // FFN hidden chunk (qkv dead)
    bf16*  xffb  = (bf16*)(ws + B_FS + 6303744);
    float* qkv1a = ws + B_FS;                // phase 2: 16384x216 fp32 (3,538,944 fs)
    float* o1all = ws + B_FS + 3538944;      // 6x16384x12 fp32 (1,179,648 fs)
    float* svs   = ws + B_FS + 4718592;      // D1SEG*768 fp32 (4,816,896 fs)
    bf16*  x1b   = (bf16*)(ws + X1_FS);
    float* ah    = ws + AH_FS;
    int*   icnt  = (int*)(ws + DI_CNT);
    int*   ibase = (int*)(ws + DI_BASE);
    int*   icur  = (int*)(ws + DI_CUR);
    int*   iord  = (int*)(ws + DI_ORD);
    float* x3d   = ws + X3D_FS;
    bf16*  bnv   = (bf16*)(ws + BNV_FS);
    float* statm = ws + STATM_FS;
    float* statr = ws + STATR_FS;
    // bf16 weights: phase-1 block + persistent block (both inside D region, disjoint from index arrays)
    bf16* WqkvB  = (bf16*)(ws + DW_FS);
    bf16* WoB    = WqkvB + 2304*768;
    bf16* WfcB   = WoB   + 768*768;
    bf16* WprojB = WfcB  + 3072*768;
    bf16* WvB    = (bf16*)(ws + DWV_FS);     // 216x768
    float* bvP   = ws + DWV_FS + 82944;      // 216
    bf16* Wa1B   = (bf16*)(ws + DWV_FS + 83200); // 16x768

    // 0. weight conversion / folding
    k_f2b<<<1024, 256, 0, stream>>>(Wqkv,  WqkvB,  2304*768);
    k_f2b<<<1024, 256, 0, stream>>>(Wo,    WoB,    768*768);
    k_f2b<<<1024, 256, 0, stream>>>(Wfc,   WfcB,   3072*768);
    k_f2b<<<1024, 256, 0, stream>>>(Wproj, WprojB, 768*3072);
    k_f2b<<<48, 256, 0, stream>>>(Wa1, Wa1B, 16*768);
    k_foldw<<<216, 256, 0, stream>>>(aqw, aqb, n3g, n3b, WvB, bvP);
    // 1. LN1 (x fp32 -> y bf16)
    k_ln<float><<<NT, 256, 0, stream>>>(x, yb, ln1g, ln1b);
    // 2. qkv GEMM (MFMA, bf16 out)
    k_gemm_mfma<bf16,0,0><<<dim3(2304/128, (NT+127)/128), 256, 0, stream>>>(yb, WqkvB, bqkv, nullptr, qkvb, NT, 2304, 768);
    // 3. flash MFMA attention -> obuf (A region; y dead)
    k_attn_mfma<<<dim3(9, NHEAD, BATCH), 256, 0, stream>>>(qkvb, yb);
    // 4. o-proj + residual(x) -> x1 bf16
    k_gemm_mfma<bf16,0,1><<<dim3(768/128, (NT+127)/128), 256, 0, stream>>>(yb, WoB, bo, x, x1b, NT, 768, 768);
    // 5. LN2 (x1 bf16 -> y2 bf16 in A)
    k_ln<bf16><<<NT, 256, 0, stream>>>(x1b, yb, ln2g, ln2b);
    // 6/7. FFN in 4 row-chunks (h chunk in B; qkv dead)
    for (int cch=0; cch<4; cch++){
        const bf16* a2 = yb + (size_t)cch*CHROWS*CDIM;
        bf16* xo = xffb + (size_t)cch*CHROWS*CDIM;
        k_gemm_mfma<bf16,1,0><<<dim3(FFDIM/128, (CHROWS+127)/128), 256, 0, stream>>>(a2, WfcB, bfc, nullptr, hb, CHROWS, FFDIM, 768);
        k_gemm_mfma<bf16,0,0><<<dim3(768/128, (CHROWS+127)/128), 256, 0, stream>>>(hb, WprojB, bproj, nullptr, xo, CHROWS, 768, FFDIM);
    }
    // 8. adapt hidden (MFMA, fp32 out, quick_gelu) N=16
    k_gemm_mfma<float,1,0><<<dim3(1, (NT+127)/128), 256, 0, stream>>>(xffb, Wa1B, ba1, nullptr, ah, NT, 16, 768);
    // 9. combine -> d_out (x2; cls rows final)
    k_comb<<<NT, 256, 0, stream>>>(x1b, xffb, ah, Wa2, ba2, out);
    // 10. cluster path: index build + gather + bn stats + gelu
    k_zero<<<32, 256, 0, stream>>>((float*)icnt, NCLUST);
    k_icount<<<NR/256, 256, 0, stream>>>(cluster, icnt, NR);
    k_iscan<<<1, 256, 0, stream>>>(icnt, ibase, icur, NCLUST);
    k_iscatter<<<NR/256, 256, 0, stream>>>(cluster, icur, iord, NR);
    k_gather_seg<<<NCLUST, 256, 0, stream>>>(out, ibase, icnt, iord, x3d);
    k_zero<<<6, 256, 0, stream>>>(statm, 1536);
    k_colstats_part<<<dim3(3, 32), 256, 0, stream>>>(x3d, NCLUST, statm, statr);
    k_colfin<<<3, 256, 0, stream>>>(statm, statr, NCLUST);
    k_bngelu<float><<<(NCLUST*CDIM+255)/256, 256, 0, stream>>>(x3d, x3d, statm, statr, bn3dg, bn3db, NCLUST*CDIM);
    // 11. view shared prep: normalize once, one GEMM for all views, batched micro-attention
    k_lnn<<<NR, 256, 0, stream>>>(out, yb);
    k_gemm_mfma<float,0,0><<<dim3(2, NR/128), 256, 0, stream>>>(yb, WvB, bvP, nullptr, qkv1a, NR, 216, 768);
    k_attnv<<<dim3(NB1, H1N, NVIEW), 128, 0, stream>>>(qkv1a, mask, o1all);
    // 12. per-view: index build + fused flat-gather + bn stats + gelu
    for (int v=0; v<NVIEW; v++){
        const int* fv = fgi + (size_t)v*NR;
        k_zero<<<32, 256, 0, stream>>>((float*)icnt, D1SEG);
        k_icount<<<NR/256, 256, 0, stream>>>(fv, icnt, NR);
        k_iscan<<<1, 256, 0, stream>>>(icnt, ibase, icur, D1SEG);
        k_iscatter<<<NR/256, 256, 0, stream>>>(fv, icur, iord, NR);
        k_gather_flat<<<D1SEG, 256, 0, stream>>>(out, o1all + (size_t)v*NR*MIDD,
                                                 apw + (size_t)v*CDIM*MIDD, apb + (size_t)v*CDIM,
                                                 ibase, icnt, iord, svs);
        k_zero<<<6, 256, 0, stream>>>(statm, 1536);
        k_colstats_part<<<dim3(3, 32), 256, 0, stream>>>(svs, D1SEG, statm, statr);
        k_colfin<<<3, 256, 0, stream>>>(statm, statr, D1SEG);
        k_bngelu<bf16><<<(D1SEG*CDIM+255)/256, 256, 0, stream>>>(svs, bnv + (size_t)v*D1SEG*CDIM, statm, statr,
                                                                 bn1dg + v*CDIM, bn1db + v*CDIM, D1SEG*CDIM);
    }
    // 13. final combine (in-place on d_out)
    k_final<<<NR, 256, 0, stream>>>(out, x3d, bnv, cluster, fgi);
}

// Round 6
// 1793.795 us; speedup vs baseline: 11.8558x; 1.2074x over previous
//
#include <hip/hip_runtime.h>
#include <hip/hip_bf16.h>
#include <math.h>

typedef unsigned int u32;
typedef __hip_bfloat16 bf16;
typedef __attribute__((ext_vector_type(8))) short bh8;
typedef __attribute__((ext_vector_type(4))) float fx4;

#define CDIM   768
#define BATCH  32
#define SEQ    513
#define NT     (BATCH*SEQ)     // 16416 rows incl cls
#define NR     16384           // BG
#define NHEAD  12
#define HD     64
#define FFDIM  3072
#define NCLUST 2048
#define D1SEG  6272
#define NVIEW  6
#define MIDD   12
#define H1N    6
#define N1V    128
#define NB1    128
#define CHROWS 8208            // FFN row chunk (2 chunks)

// ---------------- workspace layout (float-slot offsets; ≈229.8 MB total) ----
#define A_FS      ((size_t)0)          // 6,303,744 fs : y / obuf / y2 / yv  (NT*768 bf16)
#define B_FS      ((size_t)6303744)    // 18,911,232 fs: qkv bf16 | h+xffn bf16 | qkv1a+o1all+svs
#define X1_FS     ((size_t)25214976)   // 6,303,744 fs : x1 bf16
#define AH_FS     ((size_t)31518720)   // 262,656 fs   : ah fp32
#define D_FS      ((size_t)31781376)   // 9,640,064 fs : index arrays | bf16 weights
#define DTOT_FS   9640064
#define X3D_FS    ((size_t)(D_FS + DTOT_FS))          // 1,572,864 fs x3d fp32
#define BNV_FS    (X3D_FS + 1572864)                  // 14,450,688 fs bnv bf16
#define STATM_FS  (BNV_FS + 14450688)                 // 768
#define STATR_FS  (STATM_FS + 768)                    // 768
#define DI_CNT    (D_FS)
#define DI_BASE   (D_FS + 6272)
#define DI_CUR    (D_FS + 12544)
#define DI_ORD    (D_FS + 18816)
#define DW_FS     (D_FS + 40960)
#define DWV_FS    (D_FS + 3600000)

__device__ inline float b2f(bf16 v){ return __bfloat162float(v); }
__device__ inline float ldv(const float* p, size_t i){ return p[i]; }
__device__ inline float ldv(const bf16*  p, size_t i){ return __bfloat162float(p[i]); }
__device__ inline void  stv(float* p, size_t i, float v){ p[i] = v; }
__device__ inline void  stv(bf16*  p, size_t i, float v){ p[i] = __float2bfloat16(v); }
__device__ inline short f2bs(float f){ bf16 h = __float2bfloat16(f); return *(short*)&h; }
__device__ inline void gload_lds16(const bf16* g, short* l){
    __builtin_amdgcn_global_load_lds((const __attribute__((address_space(1))) void*)g,
                                     (__attribute__((address_space(3))) void*)l, 16, 0, 0);
}

// ---------------- utility ----------------

__global__ __launch_bounds__(256) void k_zero(float* p, int n){
    for (int i = blockIdx.x*256 + threadIdx.x; i < n; i += gridDim.x*256) p[i] = 0.0f;
}

__global__ __launch_bounds__(256) void k_f2b(const float* __restrict__ in, bf16* __restrict__ out, int n){
    for (int i = blockIdx.x*256 + threadIdx.x; i < n; i += gridDim.x*256)
        out[i] = __float2bfloat16(in[i]);
}

// LayerNorm over C=768, one block per row; out bf16
template<typename TI>
__global__ __launch_bounds__(256) void k_ln(const TI* __restrict__ in, bf16* __restrict__ out,
                                            const float* __restrict__ g, const float* __restrict__ b){
    int i = blockIdx.x;
    int tid = threadIdx.x;
    const TI* r = in + (size_t)i*CDIM;
    float v0 = ldv(r,(size_t)tid), v1 = ldv(r,(size_t)tid+256), v2 = ldv(r,(size_t)tid+512);
    float s  = v0+v1+v2;
    float s2 = v0*v0+v1*v1+v2*v2;
    __shared__ float t1[4], t2[4];
    #pragma unroll
    for (int o=32;o;o>>=1){ s += __shfl_down(s,o,64); s2 += __shfl_down(s2,o,64); }
    int lane = tid & 63, wid = tid >> 6;
    if (!lane){ t1[wid]=s; t2[wid]=s2; }
    __syncthreads();
    float S  = t1[0]+t1[1]+t1[2]+t1[3];
    float S2 = t2[0]+t2[1]+t2[2]+t2[3];
    float m  = S * (1.0f/CDIM);
    float var = S2 * (1.0f/CDIM) - m*m;
    float rstd = rsqrtf(var + 1e-5f);
    bf16* o_ = out + (size_t)i*CDIM;
    stv(o_,(size_t)tid,     (v0-m)*rstd*g[tid]     + b[tid]);
    stv(o_,(size_t)tid+256, (v1-m)*rstd*g[tid+256] + b[tid+256]);
    stv(o_,(size_t)tid+512, (v2-m)*rstd*g[tid+512] + b[tid+512]);
}

// normalize-only LN (affine folded into downstream weights), token-row map on input
__global__ __launch_bounds__(256) void k_lnn(const float* __restrict__ in, bf16* __restrict__ out){
    int i = blockIdx.x;
    size_t ri = (size_t)(i + (i>>9) + 1);
    int tid = threadIdx.x;
    const float* r = in + ri*CDIM;
    float v0 = r[tid], v1 = r[tid+256], v2 = r[tid+512];
    float s  = v0+v1+v2;
    float s2 = v0*v0+v1*v1+v2*v2;
    __shared__ float t1[4], t2[4];
    #pragma unroll
    for (int o=32;o;o>>=1){ s += __shfl_down(s,o,64); s2 += __shfl_down(s2,o,64); }
    int lane = tid & 63, wid = tid >> 6;
    if (!lane){ t1[wid]=s; t2[wid]=s2; }
    __syncthreads();
    float S  = t1[0]+t1[1]+t1[2]+t1[3];
    float S2 = t2[0]+t2[1]+t2[2]+t2[3];
    float m  = S * (1.0f/CDIM);
    float var = S2 * (1.0f/CDIM) - m*m;
    float rstd = rsqrtf(var + 1e-5f);
    bf16* o_ = out + (size_t)i*CDIM;
    stv(o_,(size_t)tid,     (v0-m)*rstd);
    stv(o_,(size_t)tid+256, (v1-m)*rstd);
    stv(o_,(size_t)tid+512, (v2-m)*rstd);
}

// fold per-view LN affine into view-qkv weights
__global__ __launch_bounds__(256) void k_foldw(const float* __restrict__ aqw, const float* __restrict__ aqb,
                                               const float* __restrict__ n3g, const float* __restrict__ n3b,
                                               bf16* __restrict__ Wv, float* __restrict__ bv){
    int row = blockIdx.x;                  // 0..215
    int v = row/36;
    const float* w = aqw + (size_t)row*768;
    const float* g = n3g + v*768;
    const float* b = n3b + v*768;
    int tid = threadIdx.x;
    float s = 0.0f;
    #pragma unroll
    for (int j=tid; j<768; j+=256){
        float wv = w[j];
        Wv[(size_t)row*768 + j] = __float2bfloat16(wv*g[j]);
        s += wv*b[j];
    }
    __shared__ float t1[4];
    #pragma unroll
    for (int o=32;o;o>>=1) s += __shfl_down(s,o,64);
    int lane = tid & 63, wid = tid >> 6;
    if (!lane) t1[wid]=s;
    __syncthreads();
    if (tid==0) bv[row] = aqb[row] + t1[0]+t1[1]+t1[2]+t1[3];
}

// ---------------- MFMA GEMM (async global_load_lds staging + XOR swizzle) ----------------
// out[M,N] = A[M,K](bf16) @ W[N,K]^T(bf16) + bias. 128x128 tile, BK=32, 4 waves of 64x64.
// LDS: unpadded [128 rows][32 k] shorts; global-side swizzle slot = chunk ^ ((row>>1)&3).
template<typename TO, int ACT, int RES>
__global__ __launch_bounds__(256) void k_gemm_mfma(const bf16* __restrict__ A, const bf16* __restrict__ W,
                                                   const float* __restrict__ bias, const float* __restrict__ res,
                                                   TO* __restrict__ out, int M, int N, int K){
    __shared__ short As[128*32];
    __shared__ short Ws[128*32];
    int bm = blockIdx.y*128, bn = blockIdx.x*128;
    int tid = threadIdx.x, wid = tid>>6, lane = tid&63, quad = lane>>4, l16 = lane&15;
    int wr = (wid>>1)*64, wc = (wid&1)*64;
    fx4 acc[4][4];
    #pragma unroll
    for (int i=0;i<4;i++)
        #pragma unroll
        for (int j=0;j<4;j++) acc[i][j] = (fx4){0.f,0.f,0.f,0.f};
    // staging: wave wid covers rows [wid*32, wid*32+32), 2 calls of 16 rows each
    int lrow = lane>>2;
    int gchunk = (lane&3) ^ ((lane>>3)&3);           // global k-chunk (XOR swizzle)
    int r0a0 = wid*32 + lrow,  r0a1 = wid*32 + 16 + lrow;
    int ra0 = bm + r0a0; if (ra0 > M-1) ra0 = M-1;
    int ra1 = bm + r0a1; if (ra1 > M-1) ra1 = M-1;
    int rw0 = bn + r0a0; if (rw0 > N-1) rw0 = N-1;
    int rw1 = bn + r0a1; if (rw1 > N-1) rw1 = N-1;
    const bf16* pa0 = A + (size_t)ra0*K + gchunk*8;
    const bf16* pa1 = A + (size_t)ra1*K + gchunk*8;
    const bf16* pw0 = W + (size_t)rw0*K + gchunk*8;
    const bf16* pw1 = W + (size_t)rw1*K + gchunk*8;
    short* la0 = &As[(wid*32)*32];
    short* la1 = &As[(wid*32 + 16)*32];
    short* lw0 = &Ws[(wid*32)*32];
    short* lw1 = &Ws[(wid*32 + 16)*32];
    int slotx = (l16>>1)&3;                          // read-side swizzle component
    for (int k0=0; k0<K; k0+=32){
        gload_lds16(pa0 + k0, la0);
        gload_lds16(pa1 + k0, la1);
        gload_lds16(pw0 + k0, lw0);
        gload_lds16(pw1 + k0, lw1);
        __syncthreads();
        bh8 af[4], bf_[4];
        int sa = (quad ^ slotx)*8;
        #pragma unroll
        for (int i=0;i<4;i++) af[i]  = *(const bh8*)&As[(wr + i*16 + l16)*32 + sa];
        #pragma unroll
        for (int j=0;j<4;j++) bf_[j] = *(const bh8*)&Ws[(wc + j*16 + l16)*32 + sa];
        #pragma unroll
        for (int i=0;i<4;i++)
            #pragma unroll
            for (int j=0;j<4;j++)
                acc[i][j] = __builtin_amdgcn_mfma_f32_16x16x32_bf16(af[i], bf_[j], acc[i][j], 0,0,0);
        __syncthreads();
    }
    #pragma unroll
    for (int i=0;i<4;i++){
        #pragma unroll
        for (int r=0;r<4;r++){
            int row = bm + wr + i*16 + quad*4 + r;
            if (row >= M) continue;
            #pragma unroll
            for (int j=0;j<4;j++){
                int col = bn + wc + j*16 + l16;
                if (col >= N) continue;
                float v = acc[i][j][r] + bias[col];
                if (ACT == 1) v = v / (1.0f + __expf(-1.702f*v));
                if (RES) v += res[(size_t)row*N + col];
                stv(out, (size_t)row*N + col, v);
            }
        }
    }
}

// ---------------- flash MFMA attention: block per (qtile, h, b) ----------------
#define KSTR 72
__global__ __launch_bounds__(256) void k_attn_mfma(const bf16* __restrict__ qkv, bf16* __restrict__ obuf){
    __shared__ short Ks[64*KSTR];      // [k][d]
    __shared__ short Vt[64*KSTR];      // [d][k]  (transposed)
    __shared__ short Ps[4*16*KSTR];    // per-wave P strip [16 q][64 k]
    int qt = blockIdx.x, h = blockIdx.y, b = blockIdx.z;
    int tid = threadIdx.x, wid = tid>>6, lane = tid&63, quad = lane>>4, l16 = lane&15;
    size_t base = (size_t)b*SEQ*2304;
    int q_own = qt*64 + wid*16 + l16;
    int q_cl  = q_own > 512 ? 512 : q_own;
    const bf16* qrow = qkv + base + (size_t)q_cl*2304 + h*HD;
    bh8 qa0 = *(const bh8*)(qrow + quad*8);
    bh8 qa1 = *(const bh8*)(qrow + 32 + quad*8);
    fx4 o[4];
    #pragma unroll
    for (int d=0; d<4; d++) o[d] = (fx4){0.f,0.f,0.f,0.f};
    float mrow[4] = {-1e30f,-1e30f,-1e30f,-1e30f};
    float lrow[4] = {0.f,0.f,0.f,0.f};
    int srow = tid>>2, d0 = (tid&3)*16;
    for (int kt=0; kt<9; kt++){
        int kg = kt*64 + srow;
        if (kg < SEQ){
            const bf16* krow = qkv + base + 768  + (size_t)kg*2304 + h*HD;
            const bf16* vrow = qkv + base + 1536 + (size_t)kg*2304 + h*HD;
            bh8 kv0 = *(const bh8*)(krow + d0);
            bh8 kv1 = *(const bh8*)(krow + d0 + 8);
            bh8 vv0 = *(const bh8*)(vrow + d0);
            bh8 vv1 = *(const bh8*)(vrow + d0 + 8);
            *(bh8*)&Ks[srow*KSTR + d0]     = kv0;
            *(bh8*)&Ks[srow*KSTR + d0 + 8] = kv1;
            #pragma unroll
            for (int j=0;j<8;j++){ Vt[(d0+j)*KSTR + srow] = vv0[j]; Vt[(d0+8+j)*KSTR + srow] = vv1[j]; }
        } else {
            const bh8 zv = {0,0,0,0,0,0,0,0};
            *(bh8*)&Ks[srow*KSTR + d0]     = zv;
            *(bh8*)&Ks[srow*KSTR + d0 + 8] = zv;
            #pragma unroll
            for (int j=0;j<16;j++) Vt[(d0+j)*KSTR + srow] = 0;
        }
        __syncthreads();
        fx4 s[4];
        #pragma unroll
        for (int nt=0; nt<4; nt++){
            bh8 kb0 = *(const bh8*)&Ks[(nt*16+l16)*KSTR + quad*8];
            bh8 kb1 = *(const bh8*)&Ks[(nt*16+l16)*KSTR + 32 + quad*8];
            fx4 a = (fx4){0.f,0.f,0.f,0.f};
            a = __builtin_amdgcn_mfma_f32_16x16x32_bf16(qa0, kb0, a, 0,0,0);
            a = __builtin_amdgcn_mfma_f32_16x16x32_bf16(qa1, kb1, a, 0,0,0);
            s[nt] = a;
        }
        float tmax[4] = {-1e30f,-1e30f,-1e30f,-1e30f};
        #pragma unroll
        for (int nt=0; nt<4; nt++){
            bool ok = (kt*64 + nt*16 + l16) <= 512;
            #pragma unroll
            for (int r=0;r<4;r++){
                float v = ok ? s[nt][r]*0.125f : -1e30f;
                s[nt][r] = v;
                tmax[r] = fmaxf(tmax[r], v);
            }
        }
        #pragma unroll
        for (int msk=1; msk<16; msk<<=1)
            #pragma unroll
            for (int r=0;r<4;r++) tmax[r] = fmaxf(tmax[r], __shfl_xor(tmax[r], msk, 64));
        float al[4];
        #pragma unroll
        for (int r=0;r<4;r++){
            float mn = fmaxf(mrow[r], tmax[r]);
            al[r] = __expf(mrow[r] - mn);
            mrow[r] = mn;
        }
        float ps[4] = {0.f,0.f,0.f,0.f};
        #pragma unroll
        for (int nt=0; nt<4; nt++)
            #pragma unroll
            for (int r=0;r<4;r++){
                float p = __expf(s[nt][r] - mrow[r]);
                s[nt][r] = p;
                ps[r] += p;
            }
        #pragma unroll
        for (int msk=1; msk<16; msk<<=1)
            #pragma unroll
            for (int r=0;r<4;r++) ps[r] += __shfl_xor(ps[r], msk, 64);
        #pragma unroll
        for (int r=0;r<4;r++){
            lrow[r] = lrow[r]*al[r] + ps[r];
            #pragma unroll
            for (int d=0; d<4; d++) o[d][r] *= al[r];
        }
        #pragma unroll
        for (int nt=0; nt<4; nt++)
            #pragma unroll
            for (int r=0;r<4;r++)
                Ps[(wid*16 + quad*4 + r)*KSTR + nt*16 + l16] = f2bs(s[nt][r]);
        bh8 pa0 = *(const bh8*)&Ps[(wid*16 + l16)*KSTR + quad*8];
        bh8 pa1 = *(const bh8*)&Ps[(wid*16 + l16)*KSTR + 32 + quad*8];
        #pragma unroll
        for (int dt=0; dt<4; dt++){
            bh8 vb0 = *(const bh8*)&Vt[(dt*16+l16)*KSTR + quad*8];
            bh8 vb1 = *(const bh8*)&Vt[(dt*16+l16)*KSTR + 32 + quad*8];
            o[dt] = __builtin_amdgcn_mfma_f32_16x16x32_bf16(pa0, vb0, o[dt], 0,0,0);
            o[dt] = __builtin_amdgcn_mfma_f32_16x16x32_bf16(pa1, vb1, o[dt], 0,0,0);
        }
        __syncthreads();
    }
    float inv[4];
    #pragma unroll
    for (int r=0;r<4;r++) inv[r] = 1.0f/lrow[r];
    #pragma unroll
    for (int r=0;r<4;r++){
        int q = qt*64 + wid*16 + quad*4 + r;
        if (q < SEQ){
            size_t ob = ((size_t)(b*SEQ+q))*CDIM + h*HD;
            #pragma unroll
            for (int dt=0; dt<4; dt++)
                obuf[ob + dt*16 + l16] = __float2bfloat16(o[dt][r]*inv[r]);
        }
    }
}

// x2 = x1 + xffn + 0.5*(ah @ Wa2^T + ba2) -> d_out (fp32); block per row
__global__ __launch_bounds__(256) void k_comb(const bf16* __restrict__ x1, const bf16* __restrict__ xffn,
                                              const float* __restrict__ ah, const float* __restrict__ Wa2,
                                              const float* __restrict__ ba2, float* __restrict__ x2){
    int i = blockIdx.x; int tid = threadIdx.x;
    __shared__ float ar[16];
    if (tid < 16) ar[tid] = ah[(size_t)i*16 + tid];
    __syncthreads();
    for (int c=tid; c<CDIM; c+=256){
        const float* w = Wa2 + (size_t)c*16;
        float a = ba2[c];
        #pragma unroll
        for (int mm=0; mm<16; mm++) a += ar[mm]*w[mm];
        size_t o = (size_t)i*CDIM + c;
        x2[o] = b2f(x1[o]) + b2f(xffn[o]) + 0.5f*a;
    }
}

// ---------------- segment index build ----------------
__global__ __launch_bounds__(256) void k_icount(const int* __restrict__ idx, int* __restrict__ cnt, int n){
    int i = blockIdx.x*256 + threadIdx.x;
    if (i < n) atomicAdd(&cnt[idx[i]], 1);
}

__global__ __launch_bounds__(256) void k_iscan(const int* __restrict__ cnt, int* __restrict__ base,
                                               int* __restrict__ cur, int nseg){
    __shared__ int part[256], off[256];
    int t = threadIdx.x;
    int chunk = (nseg + 255) >> 8;
    int j0 = t*chunk, j1 = j0 + chunk; if (j1 > nseg) j1 = nseg;
    int s = 0;
    for (int j=j0; j<j1; j++) s += cnt[j];
    part[t] = s; __syncthreads();
    if (t == 0){ int acc=0; for (int i=0;i<256;i++){ off[i]=acc; acc+=part[i]; } }
    __syncthreads();
    int acc = off[t];
    for (int j=j0; j<j1; j++){ base[j]=acc; cur[j]=acc; acc+=cnt[j]; }
}

__global__ __launch_bounds__(256) void k_iscatter(const int* __restrict__ idx, int* __restrict__ cur,
                                                  int* __restrict__ order, int n){
    int i = blockIdx.x*256 + threadIdx.x;
    if (i < n){
        int pos = atomicAdd(&cur[idx[i]], 1);
        order[pos] = i;
    }
}

// gather + segment max/mean for cluster path
__global__ __launch_bounds__(256) void k_gather_seg(const float* __restrict__ outx, const int* __restrict__ basep,
                                                    const int* __restrict__ cntp, const int* __restrict__ order,
                                                    float* __restrict__ dst){
    int sg = blockIdx.x; int tid = threadIdx.x;
    int n = cntp[sg], b0 = basep[sg];
    float mx[3] = {-1e30f,-1e30f,-1e30f};
    float sm[3] = {0.f,0.f,0.f};
    for (int r=0; r<n; r++){
        int i = order[b0+r];
        size_t rb = (size_t)(i + (i>>9) + 1)*CDIM;
        #pragma unroll
        for (int j=0;j<3;j++){
            float v = outx[rb + tid + j*256];
            mx[j] = fmaxf(mx[j], v); sm[j] += v;
        }
    }
    float den = (float)(n > 1 ? n : 1);
    size_t db = (size_t)sg*CDIM;
    #pragma unroll
    for (int j=0;j<3;j++)
        dst[db + tid + j*256] = (n > 0 ? mx[j] : 0.f) + sm[j]/den;
}

// per-view: flat = o1@Wp^T + bp + feat, then segment max/mean
__global__ __launch_bounds__(256) void k_gather_flat(const float* __restrict__ outx, const float* __restrict__ o1v,
                                                     const float* __restrict__ Wp, const float* __restrict__ bp,
                                                     const int* __restrict__ basep, const int* __restrict__ cntp,
                                                     const int* __restrict__ order, float* __restrict__ dst){
    int sg = blockIdx.x; int tid = threadIdx.x;
    int n = cntp[sg], b0 = basep[sg];
    float w[3][MIDD], bb[3];
    #pragma unroll
    for (int j=0;j<3;j++){
        int c = tid + j*256;
        bb[j] = bp[c];
        #pragma unroll
        for (int mm=0;mm<MIDD;mm++) w[j][mm] = Wp[(size_t)c*MIDD + mm];
    }
    float mx[3] = {-1e30f,-1e30f,-1e30f};
    float sm[3] = {0.f,0.f,0.f};
    for (int r=0; r<n; r++){
        int i = order[b0+r];
        const float* orow = o1v + (size_t)i*MIDD;
        float ov[MIDD];
        #pragma unroll
        for (int mm=0;mm<MIDD;mm++) ov[mm] = orow[mm];
        size_t rb = (size_t)(i + (i>>9) + 1)*CDIM;
        #pragma unroll
        for (int j=0;j<3;j++){
            float a = bb[j];
            #pragma unroll
            for (int mm=0;mm<MIDD;mm++) a += ov[mm]*w[j][mm];
            a += outx[rb + tid + j*256];
            mx[j] = fmaxf(mx[j], a); sm[j] += a;
        }
    }
    float den = (float)(n > 1 ? n : 1);
    size_t db = (size_t)sg*CDIM;
    #pragma unroll
    for (int j=0;j<3;j++)
        dst[db + tid + j*256] = (n > 0 ? mx[j] : 0.f) + sm[j]/den;
}

// two-stage column stats
__global__ __launch_bounds__(256) void k_colstats_part(const float* __restrict__ in, int rows,
                                                       float* __restrict__ sumv, float* __restrict__ sumsq){
    int c = blockIdx.x*256 + threadIdx.x;
    if (c >= CDIM) return;
    int chunk = (rows + 31) >> 5;
    int r0 = blockIdx.y*chunk;
    int r1 = r0 + chunk; if (r1 > rows) r1 = rows;
    float s = 0.0f, s2 = 0.0f;
    for (int r=r0; r<r1; r++){
        float v = in[(size_t)r*CDIM + c];
        s += v; s2 += v*v;
    }
    atomicAdd(&sumv[c], s);
    atomicAdd(&sumsq[c], s2);
}

__global__ __launch_bounds__(256) void k_colfin(float* __restrict__ sumv, float* __restrict__ sumsq, int rows){
    int c = blockIdx.x*256 + threadIdx.x;
    if (c >= CDIM) return;
    float m = sumv[c] / (float)rows;
    float var = sumsq[c] / (float)rows - m*m;
    sumv[c]  = m;
    sumsq[c] = rsqrtf(fmaxf(var, 0.0f) + 1e-5f);
}

template<typename TO>
__global__ __launch_bounds__(256) void k_bngelu(const float* __restrict__ in, TO* __restrict__ outp,
                                                const float* __restrict__ m, const float* __restrict__ r,
                                                const float* __restrict__ g, const float* __restrict__ b, int n){
    int i = blockIdx.x*256 + threadIdx.x;
    if (i >= n) return;
    int c = i - (i/CDIM)*CDIM;
    float y = (in[i]-m[c])*r[c]*g[c] + b[c];
    stv(outp, (size_t)i, 0.5f*y*(1.0f + erff(y*0.70710678118654752f)));
}

// per-view micro attention: block per (segblock, view); 256 threads = 2 head-groups x 128 rows.
// mask tile + Q/K/V staged in LDS once per block, shared by all 6 heads.
#define MSTR 33    // mask row stride in dwords (132 B)
__global__ __launch_bounds__(256) void k_attnv(const float* __restrict__ qkv1a,
                                               const unsigned char* __restrict__ mask,
                                               float* __restrict__ o1all){
    __shared__ float Qs[N1V][13], Ksv[N1V][13], Vsv[N1V][13];
    __shared__ int   Ms[N1V*MSTR];
    int blk = blockIdx.x, v = blockIdx.y;
    int tid = threadIdx.x;
    // stage Q/K/V: threads 0..127, one row each (9 float4 = 36 floats)
    if (tid < N1V){
        const float4* rp = (const float4*)(qkv1a + (size_t)(blk*N1V + tid)*216 + v*36);
        #pragma unroll
        for (int j=0;j<3;j++){
            float4 q4 = rp[j], k4 = rp[3+j], v4 = rp[6+j];
            Qs[tid][j*4+0]=q4.x; Qs[tid][j*4+1]=q4.y; Qs[tid][j*4+2]=q4.z; Qs[tid][j*4+3]=q4.w;
            Ksv[tid][j*4+0]=k4.x; Ksv[tid][j*4+1]=k4.y; Ksv[tid][j*4+2]=k4.z; Ksv[tid][j*4+3]=k4.w;
            Vsv[tid][j*4+0]=v4.x; Vsv[tid][j*4+1]=v4.y; Vsv[tid][j*4+2]=v4.z; Vsv[tid][j*4+3]=v4.w;
        }
    }
    // stage mask tile (16 KB) coalesced, write at stride 132 B
    {
        const int4* mp = (const int4*)(mask + ((size_t)v*NB1 + blk)*N1V*N1V);
        #pragma unroll
        for (int it=0; it<4; it++){
            int e = tid + it*256;            // 0..1023 int4s
            int4 m4 = mp[e];
            int row = e >> 3, c4 = (e & 7)*4;
            Ms[row*MSTR + c4 + 0] = m4.x;
            Ms[row*MSTR + c4 + 1] = m4.y;
            Ms[row*MSTR + c4 + 2] = m4.z;
            Ms[row*MSTR + c4 + 3] = m4.w;
        }
    }
    __syncthreads();
    int n = tid & 127, hg = tid >> 7;
    const float scale = 0.28867513459481287f; // 12^-0.5
    #pragma unroll
    for (int hh=0; hh<3; hh++){
        int h = hg*3 + hh;
        float q0 = Qs[n][h*2], q1 = Qs[n][h*2+1];
        float m = -1e30f;
        #pragma unroll 4
        for (int k4=0; k4<32; k4++){
            int mw = Ms[n*MSTR + k4];
            #pragma unroll
            for (int j=0;j<4;j++){
                int k = k4*4 + j;
                float s = (q0*Ksv[k][h*2] + q1*Ksv[k][h*2+1])*scale + (((mw>>(j*8))&0xFF) ? -100000.0f : 0.0f);
                m = fmaxf(m, s);
            }
        }
        float l = 0.f, o0 = 0.f, o1v = 0.f;
        #pragma unroll 4
        for (int k4=0; k4<32; k4++){
            int mw = Ms[n*MSTR + k4];
            #pragma unroll
            for (int j=0;j<4;j++){
                int k = k4*4 + j;
                float s = (q0*Ksv[k][h*2] + q1*Ksv[k][h*2+1])*scale + (((mw>>(j*8))&0xFF) ? -100000.0f : 0.0f);
                float p = __expf(s - m);
                l += p; o0 += p*Vsv[k][h*2]; o1v += p*Vsv[k][h*2+1];
            }
        }
        float inv = 1.0f/l;
        float* orow = o1all + ((size_t)v*NR + blk*N1V + n)*MIDD + h*2;
        orow[0] = o0*inv; orow[1] = o1v*inv;
    }
}

// cossim + sims-normalize + weighted sum + residual; block per token row; in-place on d_out
__global__ __launch_bounds__(256) void k_final(float* __restrict__ outx, const float* __restrict__ x3d,
                                               const bf16* __restrict__ bnv, const int* __restrict__ cluster,
                                               const int* __restrict__ fgi){
    int i = blockIdx.x; int tid = threadIdx.x;
    int cl = cluster[i];
    const float* xr = x3d + (size_t)cl*CDIM;
    const bf16* pr[NVIEW];
    #pragma unroll
    for (int v=0; v<NVIEW; v++)
        pr[v] = bnv + ((size_t)v*D1SEG + fgi[(size_t)v*NR + i])*CDIM;
    size_t rb = (size_t)(i + (i>>9) + 1)*CDIM;
    float pv[NVIEW][3], ft[3];
    float dotv[NVIEW] = {0,0,0,0,0,0};
    float np2[NVIEW]  = {0,0,0,0,0,0};
    float nx2 = 0.0f;
    #pragma unroll
    for (int j=0; j<3; j++){
        int c = tid + j*256;
        float xv = xr[c]; nx2 += xv*xv;
        ft[j] = outx[rb + c];
        #pragma unroll
        for (int v=0; v<NVIEW; v++){
            float p = b2f(pr[v][c]); pv[v][j] = p;
            dotv[v] += p*xv; np2[v] += p*p;
        }
    }
    __shared__ float part[4*13];
    __shared__ float ssim[NVIEW];
    float vals[13];
    vals[0] = nx2;
    #pragma unroll
    for (int v=0; v<NVIEW; v++){ vals[1+v] = dotv[v]; vals[7+v] = np2[v]; }
    int lane = tid & 63, wid = tid >> 6;
    #pragma unroll
    for (int k=0; k<13; k++){
        float w = vals[k];
        #pragma unroll
        for (int o=32;o;o>>=1) w += __shfl_down(w,o,64);
        if (!lane) part[wid*13 + k] = w;
    }
    __syncthreads();
    if (tid == 0){
        float tot[13];
        #pragma unroll
        for (int k=0; k<13; k++) tot[k] = part[k] + part[13+k] + part[26+k] + part[39+k];
        float nb = fmaxf(sqrtf(tot[0]), 1e-8f);
        float sv[NVIEW]; float ssumv = 0.0f;
        #pragma unroll
        for (int v=0; v<NVIEW; v++){
            float na = fmaxf(sqrtf(tot[7+v]), 1e-8f);
            float cs = tot[1+v] / (na*nb);
            sv[v] = (cs + 1.0f)*0.5f;
            ssumv += sv[v];
        }
        #pragma unroll
        for (int v=0; v<NVIEW; v++) ssim[v] = sv[v]/ssumv;
    }
    __syncthreads();
    #pragma unroll
    for (int j=0; j<3; j++){
        int c = tid + j*256;
        float xs = 0.0f;
        #pragma unroll
        for (int v=0; v<NVIEW; v++) xs += ssim[v]*pv[v][j];
        outx[rb + c] = ft[j] + 0.3f*xs;
    }
}

// ---------------- host launcher ----------------
extern "C" void kernel_launch(void* const* d_in, const int* in_sizes, int n_in,
                              void* d_out, int out_size, void* d_ws, size_t ws_size,
                              hipStream_t stream){
    const float* x     = (const float*)d_in[0];
    const float* ln1g  = (const float*)d_in[1];
    const float* ln1b  = (const float*)d_in[2];
    const float* ln2g  = (const float*)d_in[3];
    const float* ln2b  = (const float*)d_in[4];
    const float* Wqkv  = (const float*)d_in[5];
    const float* bqkv  = (const float*)d_in[6];
    const float* Wo    = (const float*)d_in[7];
    const float* bo    = (const float*)d_in[8];
    const float* Wfc   = (const float*)d_in[9];
    const float* bfc   = (const float*)d_in[10];
    const float* Wproj = (const float*)d_in[11];
    const float* bproj = (const float*)d_in[12];
    const float* Wa1   = (const float*)d_in[13];
    const float* ba1   = (const float*)d_in[14];
    const float* Wa2   = (const float*)d_in[15];
    const float* ba2   = (const float*)d_in[16];
    const float* bn3dg = (const float*)d_in[17];
    const float* bn3db = (const float*)d_in[18];
    const float* bn1dg = (const float*)d_in[19];
    const float* bn1db = (const float*)d_in[20];
    const float* n3g   = (const float*)d_in[21];
    const float* n3b   = (const float*)d_in[22];
    const float* aqw   = (const float*)d_in[23];
    const float* aqb   = (const float*)d_in[24];
    const float* apw   = (const float*)d_in[25];
    const float* apb   = (const float*)d_in[26];
    const int*   cluster = (const int*)d_in[27];
    const int*   fgi     = (const int*)d_in[28];
    const unsigned char* mask = (const unsigned char*)d_in[29];
    float* out = (float*)d_out;
    float* ws  = (float*)d_ws;

    bf16*  yb    = (bf16*)(ws + A_FS);
    bf16*  qkvb  = (bf16*)(ws + B_FS);
    bf16*  hb    = (bf16*)(ws + B_FS);          // FFN hidden chunk (8208 rows)
    bf16*  xffb  = (bf16*)(ws + B_FS + 12607488);
    float* qkv1a = ws + B_FS;                   // phase 2
    float* o1all = ws + B_FS + 3538944;
    float* svs   = ws + B_FS + 4718592;
    bf16*  x1b   = (bf16*)(ws + X1_FS);
    float* ah    = ws + AH_FS;
    int*   icnt  = (int*)(ws + DI_CNT);
    int*   ibase = (int*)(ws + DI_BASE);
    int*   icur  = (int*)(ws + DI_CUR);
    int*   iord  = (int*)(ws + DI_ORD);
    float* x3d   = ws + X3D_FS;
    bf16*  bnv   = (bf16*)(ws + BNV_FS);
    float* statm = ws + STATM_FS;
    float* statr = ws + STATR_FS;
    bf16* WqkvB  = (bf16*)(ws + DW_FS);
    bf16* WoB    = WqkvB + 2304*768;
    bf16* WfcB   = WoB   + 768*768;
    bf16* WprojB = WfcB  + 3072*768;
    bf16* WvB    = (bf16*)(ws + DWV_FS);        // 216x768
    float* bvP   = ws + DWV_FS + 82944;
    bf16* Wa1B   = (bf16*)(ws + DWV_FS + 83200);

    // 0. weight conversion / folding
    k_f2b<<<1024, 256, 0, stream>>>(Wqkv,  WqkvB,  2304*768);
    k_f2b<<<1024, 256, 0, stream>>>(Wo,    WoB,    768*768);
    k_f2b<<<1024, 256, 0, stream>>>(Wfc,   WfcB,   3072*768);
    k_f2b<<<1024, 256, 0, stream>>>(Wproj, WprojB, 768*3072);
    k_f2b<<<48, 256, 0, stream>>>(Wa1, Wa1B, 16*768);
    k_foldw<<<216, 256, 0, stream>>>(aqw, aqb, n3g, n3b, WvB, bvP);
    // 1. LN1
    k_ln<float><<<NT, 256, 0, stream>>>(x, yb, ln1g, ln1b);
    // 2. qkv GEMM
    k_gemm_mfma<bf16,0,0><<<dim3(2304/128, (NT+127)/128), 256, 0, stream>>>(yb, WqkvB, bqkv, nullptr, qkvb, NT, 2304, 768);
    // 3. flash attention
    k_attn_mfma<<<dim3(9, NHEAD, BATCH), 256, 0, stream>>>(qkvb, yb);
    // 4. o-proj + residual(x)
    k_gemm_mfma<bf16,0,1><<<dim3(768/128, (NT+127)/128), 256, 0, stream>>>(yb, WoB, bo, x, x1b, NT, 768, 768);
    // 5. LN2
    k_ln<bf16><<<NT, 256, 0, stream>>>(x1b, yb, ln2g, ln2b);
    // 6/7. FFN in 2 row-chunks
    for (int cch=0; cch<2; cch++){
        const bf16* a2 = yb + (size_t)cch*CHROWS*CDIM;
        bf16* xo = xffb + (size_t)cch*CHROWS*CDIM;
        k_gemm_mfma<bf16,1,0><<<dim3(FFDIM/128, (CHROWS+127)/128), 256, 0, stream>>>(a2, WfcB, bfc, nullptr, hb, CHROWS, FFDIM, 768);
        k_gemm_mfma<bf16,0,0><<<dim3(768/128, (CHROWS+127)/128), 256, 0, stream>>>(hb, WprojB, bproj, nullptr, xo, CHROWS, 768, FFDIM);
    }
    // 8. adapt hidden
    k_gemm_mfma<float,1,0><<<dim3(1, (NT+127)/128), 256, 0, stream>>>(xffb, Wa1B, ba1, nullptr, ah, NT, 16, 768);
    // 9. combine -> d_out
    k_comb<<<NT, 256, 0, stream>>>(x1b, xffb, ah, Wa2, ba2, out);
    // 10. cluster path
    k_zero<<<32, 256, 0, stream>>>((float*)icnt, NCLUST);
    k_icount<<<NR/256, 256, 0, stream>>>(cluster, icnt, NR);
    k_iscan<<<1, 256, 0, stream>>>(icnt, ibase, icur, NCLUST);
    k_iscatter<<<NR/256, 256, 0, stream>>>(cluster, icur, iord, NR);
    k_gather_seg<<<NCLUST, 256, 0, stream>>>(out, ibase, icnt, iord, x3d);
    k_zero<<<6, 256, 0, stream>>>(statm, 1536);
    k_colstats_part<<<dim3(3, 32), 256, 0, stream>>>(x3d, NCLUST, statm, statr);
    k_colfin<<<3, 256, 0, stream>>>(statm, statr, NCLUST);
    k_bngelu<float><<<(NCLUST*CDIM+255)/256, 256, 0, stream>>>(x3d, x3d, statm, statr, bn3dg, bn3db, NCLUST*CDIM);
    // 11. view shared prep
    k_lnn<<<NR, 256, 0, stream>>>(out, yb);
    k_gemm_mfma<float,0,0><<<dim3(2, NR/128), 256, 0, stream>>>(yb, WvB, bvP, nullptr, qkv1a, NR, 216, 768);
    k_attnv<<<dim3(NB1, NVIEW), 256, 0, stream>>>(qkv1a, mask, o1all);
    // 12. per-view: index build + fused flat-gather + bn stats + gelu
    for (int v=0; v<NVIEW; v++){
        const int* fv = fgi + (size_t)v*NR;
        k_zero<<<32, 256, 0, stream>>>((float*)icnt, D1SEG);
        k_icount<<<NR/256, 256, 0, stream>>>(fv, icnt, NR);
        k_iscan<<<1, 256, 0, stream>>>(icnt, ibase, icur, D1SEG);
        k_iscatter<<<NR/256, 256, 0, stream>>>(fv, icur, iord, NR);
        k_gather_flat<<<D1SEG, 256, 0, stream>>>(out, o1all + (size_t)v*NR*MIDD,
                                                 apw + (size_t)v*CDIM*MIDD, apb + (size_t)v*CDIM,
                                                 ibase, icnt, iord, svs);
        k_zero<<<6, 256, 0, stream>>>(statm, 1536);
        k_colstats_part<<<dim3(3, 32), 256, 0, stream>>>(svs, D1SEG, statm, statr);
        k_colfin<<<3, 256, 0, stream>>>(statm, statr, D1SEG);
        k_bngelu<bf16><<<(D1SEG*CDIM+255)/256, 256, 0, stream>>>(svs, bnv + (size_t)v*D1SEG*CDIM, statm, statr,
                                                                 bn1dg + v*CDIM, bn1db + v*CDIM, D1SEG*CDIM);
    }
    // 13. final combine
    k_final<<<NR, 256, 0, stream>>>(out, x3d, bnv, cluster, fgi);
}